// Round 9
// baseline (406.782 us; speedup 1.0000x reference)
//
#include <hip/hip_runtime.h>
#include <hip/hip_fp16.h>
#include <math.h>

typedef unsigned long long u64;

#define NN 8192
#define EE 81920
#define E2C 1310720
#define HSZ (1 << 18)
#define HMASK (HSZ - 1)
#define NBIN 320     // dst >> 8 : bins of 256 edge-nodes
#define BCAP 4800    // Poisson(4096), +11 sigma
#define SBITS 17     // src index bits in packed u32 payload
#define WST 129      // Wl stride (odd -> conflict-free b32 reads)
#define TST 130      // Tacc stride

__device__ __forceinline__ float wsum(float v) {
#pragma unroll
  for (int m = 32; m > 0; m >>= 1) v += __shfl_xor(v, m, 64);
  return v;
}
__device__ __forceinline__ float lrelu(float x) { return x > 0.f ? x : 0.2f * x; }
__device__ __forceinline__ unsigned packh2(float a, float b) {
  __half2 h = __floats2half2_rn(a, b);
  return *reinterpret_cast<unsigned*>(&h);
}
__device__ __forceinline__ void atomic_pk_add_f16(unsigned* addr, unsigned data) {
  asm volatile("global_atomic_pk_add_f16 %0, %1, off" :: "v"(addr), "v"(data) : "memory");
}
__device__ __forceinline__ int hfind(const int* __restrict__ keys, int key) {
  unsigned i = ((unsigned)key * 2654435761u) >> 14 & HMASK;
  while (true) {
    int k = keys[i];
    if (k == key) return (int)i;
    if (k == -1) return -1;
    i = (i + 1) & HMASK;
  }
}
// bf16x2 helpers: low 16 bits = first (even-dim) element
__device__ __forceinline__ float2 bf2f(unsigned u) {
  return make_float2(__uint_as_float(u << 16), __uint_as_float(u & 0xffff0000u));
}
__device__ __forceinline__ unsigned f2bf(float a, float b) {
  unsigned ua = __float_as_uint(a);
  ua = (ua + 0x7fffu + ((ua >> 16) & 1u)) >> 16;
  unsigned ub = __float_as_uint(b);
  ub = ((ub + 0x7fffu + ((ub >> 16) & 1u)) >> 16) << 16;
  return (ua & 0xffffu) | ub;
}

// A: init + x->bf16 + per-block combo in LDS + node scalars. 512 blocks.
__global__ __launch_bounds__(256) void kA(const float* __restrict__ x,
                                          const float* __restrict__ embed,
                                          const float* __restrict__ gw,
                                          const float* __restrict__ att_s,
                                          const float* __restrict__ att_d,
                                          const float* __restrict__ lin_W,
                                          float4* __restrict__ pN, float4* __restrict__ qN,
                                          unsigned* __restrict__ xb,
                                          int* __restrict__ hKeys, unsigned* __restrict__ hPair,
                                          int* __restrict__ colCnt, float* __restrict__ gvec,
                                          unsigned* __restrict__ done, unsigned* __restrict__ gCur) {
  __shared__ float sm[768];  // cA | cD | cZ
  int t = threadIdx.x, bid = blockIdx.x;
  int lane = t & 63, wv = t >> 6;
  for (int i = bid * 256 + t; i < HSZ; i += 512 * 256) { hKeys[i] = -1; hPair[i] = 0u; }
  for (int i = bid * 256 + t; i < NN; i += 512 * 256) colCnt[i] = 0;
  if (bid == 0) {
    if (t < 128) gvec[t] = 0.f;
    if (t == 0) *done = 0u;
    for (int i = t; i < NBIN; i += 256) gCur[i] = 0u;
  }
  {  // x -> bf16 (8 elems/thread)
    const float4* x4 = (const float4*)x;
    float4 a = x4[bid * 512 + t * 2];
    float4 b = x4[bid * 512 + t * 2 + 1];
    uint4 o;
    o.x = f2bf(a.x, a.y); o.y = f2bf(a.z, a.w);
    o.z = f2bf(b.x, b.y); o.w = f2bf(b.z, b.w);
    ((uint4*)xb)[bid * 256 + t] = o;
  }
  {
    float sa = 0.f, sd = 0.f, sz = 0.f;
#pragma unroll 8
    for (int k = 0; k < 64; k++) {
      float w = gw[t * 64 + k];
      sa += w * att_s[k]; sd += w * att_d[k]; sz += w * lin_W[k];
    }
    sm[t] = sa; sm[256 + t] = sd; sm[512 + t] = sz;
  }
  __syncthreads();
#pragma unroll
  for (int j = 0; j < 4; j++) {
    int n = bid * 16 + wv * 4 + j;
    float e0 = embed[n * 128 + lane], e1 = embed[n * 128 + 64 + lane];
    float pA = wsum(e0 * sm[lane] + e1 * sm[64 + lane]);
    float qA = wsum(e0 * sm[128 + lane] + e1 * sm[192 + lane]);
    float pD = wsum(e0 * sm[256 + lane] + e1 * sm[320 + lane]);
    float qD = wsum(e0 * sm[384 + lane] + e1 * sm[448 + lane]);
    float pZ = wsum(e0 * sm[512 + lane] + e1 * sm[576 + lane]);
    float qZ = wsum(e0 * sm[640 + lane] + e1 * sm[704 + lane]);
    if (lane == 0) pN[n] = make_float4(pA, pD, pZ, 0.f);
    if (lane == 1) qN[n] = make_float4(qA, qD, qZ, 0.f);
  }
}

// B: per-edge scalars + col histogram
__global__ void kB(const int* __restrict__ row, const int* __restrict__ col,
                   const float4* __restrict__ pN, const float4* __restrict__ qN,
                   float2* __restrict__ asz, float* __restrict__ ad, int* __restrict__ colCnt) {
  int e = blockIdx.x * 256 + threadIdx.x;
  int r = row[e], c = col[e];
  float4 p = pN[r];
  float4 q = qN[c];
  asz[e] = make_float2(p.x + q.x, p.z + q.z);  // {a_s, z}
  ad[e] = p.y + q.y;
  atomicAdd(&colCnt[c], 1);
}

// C: blocks 0..319 partition edge2 into 320 dst bins; block 320 scans colCnt.
__global__ __launch_bounds__(256) void kC(const int* __restrict__ src2, const int* __restrict__ dst2,
                                          const int* __restrict__ colCnt, int* __restrict__ colOffs,
                                          int* __restrict__ colCur,
                                          unsigned* __restrict__ gCur, unsigned* __restrict__ bucket) {
  int t = threadIdx.x;
  if (blockIdx.x == 320) {
    __shared__ int sd32[256];
    int beg = t * 32;
    int s = 0;
#pragma unroll 8
    for (int i = 0; i < 32; i++) s += colCnt[beg + i];
    sd32[t] = s;
    __syncthreads();
    for (int o = 1; o < 256; o <<= 1) {
      int v = (t >= o) ? sd32[t - o] : 0;
      __syncthreads();
      sd32[t] += v;
      __syncthreads();
    }
    int run = (t == 0) ? 0 : sd32[t - 1];
    for (int i = 0; i < 32; i++) {
      colOffs[beg + i] = run;
      colCur[beg + i] = run;
      run += colCnt[beg + i];
    }
    if (t == 255) colOffs[NN] = run;
    return;
  }
  __shared__ unsigned hist[NBIN], base[NBIN], lcur[NBIN];
  for (int i = t; i < NBIN; i += 256) { hist[i] = 0u; lcur[i] = 0u; }
  __syncthreads();
  int blockBase = blockIdx.x * 4096;
  int4 dv[4];
#pragma unroll
  for (int j = 0; j < 4; j++) {
    dv[j] = *(const int4*)&dst2[blockBase + j * 1024 + t * 4];
    atomicAdd(&hist[dv[j].x >> 8], 1u);
    atomicAdd(&hist[dv[j].y >> 8], 1u);
    atomicAdd(&hist[dv[j].z >> 8], 1u);
    atomicAdd(&hist[dv[j].w >> 8], 1u);
  }
  __syncthreads();
  for (int i = t; i < NBIN; i += 256)
    if (hist[i]) base[i] = atomicAdd(&gCur[i], hist[i]);
  __syncthreads();
#pragma unroll
  for (int j = 0; j < 4; j++) {
    int4 sv = *(const int4*)&src2[blockBase + j * 1024 + t * 4];
    int ss[4] = {sv.x, sv.y, sv.z, sv.w};
    int dd[4] = {dv[j].x, dv[j].y, dv[j].z, dv[j].w};
#pragma unroll
    for (int k = 0; k < 4; k++) {
      int s = ss[k], d = dd[k];
      int b = d >> 8;
      unsigned r = atomicAdd(&lcur[b], 1u);
      unsigned pos = base[b] + r;
      if (pos < BCAP) bucket[(size_t)b * BCAP + pos] = ((unsigned)(d & 255) << SBITS) | (unsigned)s;
    }
  }
}

// D: per-bin reduce (4-wide ILP) + gate + hash insert
__global__ __launch_bounds__(256) void kD(const int* __restrict__ row, const int* __restrict__ col,
                                          const float2* __restrict__ asz, const float* __restrict__ ad,
                                          const unsigned* __restrict__ bucket, const unsigned* __restrict__ gCur,
                                          const float* __restrict__ gat_b, const float* __restrict__ lin_W,
                                          const float* __restrict__ lin_b, const float* __restrict__ noise,
                                          const float* __restrict__ tmp,
                                          int* __restrict__ hKeys, unsigned* __restrict__ hPair) {
  __shared__ float acc[512];
  __shared__ float adl[256];
  int b = blockIdx.x, t = threadIdx.x, lane = t & 63;
  acc[2 * t] = 0.f; acc[2 * t + 1] = 0.f; adl[t] = ad[b * 256 + t];
  __syncthreads();
  int cnt = min((int)gCur[b], BCAP);
  const unsigned* bp = bucket + (size_t)b * BCAP;
  const unsigned SM = (1u << SBITS) - 1;
  int i = t;
  for (; i + 768 < cnt; i += 1024) {
    unsigned u0 = bp[i], u1 = bp[i + 256], u2 = bp[i + 512], u3 = bp[i + 768];
    float2 az0 = asz[u0 & SM], az1 = asz[u1 & SM], az2 = asz[u2 & SM], az3 = asz[u3 & SM];
    int l0 = u0 >> SBITS, l1 = u1 >> SBITS, l2 = u2 >> SBITS, l3 = u3 >> SBITS;
    float ea0 = __expf(lrelu(az0.x + adl[l0]));
    float ea1 = __expf(lrelu(az1.x + adl[l1]));
    float ea2 = __expf(lrelu(az2.x + adl[l2]));
    float ea3 = __expf(lrelu(az3.x + adl[l3]));
    atomicAdd(&acc[2 * l0], ea0); atomicAdd(&acc[2 * l0 + 1], ea0 * az0.y);
    atomicAdd(&acc[2 * l1], ea1); atomicAdd(&acc[2 * l1 + 1], ea1 * az1.y);
    atomicAdd(&acc[2 * l2], ea2); atomicAdd(&acc[2 * l2 + 1], ea2 * az2.y);
    atomicAdd(&acc[2 * l3], ea3); atomicAdd(&acc[2 * l3 + 1], ea3 * az3.y);
  }
  for (; i < cnt; i += 256) {
    unsigned u = bp[i];
    float2 az = asz[u & SM];
    int l = u >> SBITS;
    float ea = __expf(lrelu(az.x + adl[l]));
    atomicAdd(&acc[2 * l], ea);
    atomicAdd(&acc[2 * l + 1], ea * az.y);
  }
  __syncthreads();
  float gb = wsum(gat_b[lane] * lin_W[lane]) + lin_b[0];
  float itmp = 1.f / tmp[0];
  {
    int e = b * 256 + t;
    float2 szv = asz[e];
    float eself = __expf(lrelu(szv.x + adl[t]));
    float la = (acc[2 * t + 1] + eself * szv.y) / (acc[2 * t] + eself) + gb;
    float ns = noise[e];
    float g = (logf(ns) - log1pf(-ns) + la) * itmp;
    float gate = 1.f / (1.f + __expf(-g));
    int key = row[e] * NN + col[e];
    unsigned hi = ((unsigned)key * 2654435761u) >> 14 & HMASK;
    while (true) {
      int old = atomicCAS(&hKeys[hi], -1, key);
      if (old == -1 || old == key) break;
      hi = (hi + 1) & HMASK;
    }
    atomic_pk_add_f16(&hPair[hi], packh2(1.0f, gate));
  }
}

// E: edge_mask -> w; CSR scatter of packed (row | local<<16, w)
__global__ void kE(const int* __restrict__ row, const int* __restrict__ col,
                   const int* __restrict__ hKeys, const unsigned* __restrict__ hPair,
                   int* __restrict__ colCur, int2* __restrict__ csrP) {
  int e = blockIdx.x * 256 + threadIdx.x;
  int r = row[e], c = col[e];
  int s1 = hfind(hKeys, r * NN + c);
  unsigned u1 = hPair[s1];
  __half2 h1 = *reinterpret_cast<__half2*>(&u1);
  float cv = __low2float(h1), g1 = __high2float(h1);
  int s2 = hfind(hKeys, c * NN + r);
  float g2 = 0.f;
  if (s2 >= 0) {
    unsigned u2 = hPair[s2];
    g2 = __high2float(*reinterpret_cast<__half2*>(&u2));
  }
  float em = cv * 0.5f * (g1 + g2);
  float w = 1.f / (1.f + __expf(-em));
  int pos = atomicAdd(&colCur[c], 1);
  csrP[pos] = make_int2(r | ((c & 15) << 16), __float_as_int(w));  // node-local in bits 16..19
}

// ---- shared layer body: edge-parallel gather into LDS + shfl GEMM ----
// On return acc[j] = output dims {2lane, 2lane+1} of node nb+wv*4+j (pre-relu).
#define LAYER_BODY(XB, NB)                                                          \
  {                                                                                 \
    for (int i = t; i < 4096; i += 256) {  /* stage W transposed bf16 */            \
      float4 a = W4[i];                                                             \
      int k = i >> 5, o2 = (i & 31) * 2;                                            \
      Wl[o2 * WST + k] = f2bf(a.x, a.y);                                            \
      Wl[(o2 + 1) * WST + k] = f2bf(a.z, a.w);                                      \
    }                                                                               \
    for (int i = t; i < 16 * TST; i += 256) Tacc[i] = 0.f;                          \
    if (t < 16) wsAcc[t] = 0.f;                                                     \
    if (t < 17) offsL[t] = colOffs[(NB) + t];                                       \
    __syncthreads();                                                                \
    int beg = offsL[0], endE = offsL[16];                                           \
    int e = beg + (wv << 2);                                                        \
    for (; e + 3 < endE; e += 16) {                                                 \
      int2 q0 = csrP[e], q1 = csrP[e + 1], q2 = csrP[e + 2], q3 = csrP[e + 3];      \
      unsigned u0 = (XB)[(q0.x & 0xffff) * 64 + lane];                              \
      unsigned u1 = (XB)[(q1.x & 0xffff) * 64 + lane];                              \
      unsigned u2 = (XB)[(q2.x & 0xffff) * 64 + lane];                              \
      unsigned u3 = (XB)[(q3.x & 0xffff) * 64 + lane];                              \
      float w0 = __int_as_float(q0.y), w1 = __int_as_float(q1.y);                   \
      float w2 = __int_as_float(q2.y), w3 = __int_as_float(q3.y);                   \
      int n0 = q0.x >> 16, n1 = q1.x >> 16, n2 = q2.x >> 16, n3 = q3.x >> 16;       \
      float2 f0 = bf2f(u0), f1 = bf2f(u1), f2v = bf2f(u2), f3 = bf2f(u3);           \
      atomicAdd(&Tacc[n0 * TST + 2 * lane], w0 * f0.x);                             \
      atomicAdd(&Tacc[n0 * TST + 2 * lane + 1], w0 * f0.y);                         \
      atomicAdd(&Tacc[n1 * TST + 2 * lane], w1 * f1.x);                             \
      atomicAdd(&Tacc[n1 * TST + 2 * lane + 1], w1 * f1.y);                         \
      atomicAdd(&Tacc[n2 * TST + 2 * lane], w2 * f2v.x);                            \
      atomicAdd(&Tacc[n2 * TST + 2 * lane + 1], w2 * f2v.y);                        \
      atomicAdd(&Tacc[n3 * TST + 2 * lane], w3 * f3.x);                             \
      atomicAdd(&Tacc[n3 * TST + 2 * lane + 1], w3 * f3.y);                         \
      if (lane == 0) {                                                              \
        atomicAdd(&wsAcc[n0], w0); atomicAdd(&wsAcc[n1], w1);                       \
        atomicAdd(&wsAcc[n2], w2); atomicAdd(&wsAcc[n3], w3);                       \
      }                                                                             \
    }                                                                               \
    for (int ee = e; ee < min(e + 4, endE); ee++) {                                 \
      int2 q = csrP[ee];                                                            \
      unsigned u = (XB)[(q.x & 0xffff) * 64 + lane];                                \
      float w = __int_as_float(q.y);                                                \
      int nl = q.x >> 16;                                                           \
      float2 f = bf2f(u);                                                           \
      atomicAdd(&Tacc[nl * TST + 2 * lane], w * f.x);                               \
      atomicAdd(&Tacc[nl * TST + 2 * lane + 1], w * f.y);                           \
      if (lane == 0) atomicAdd(&wsAcc[nl], w);                                      \
    }                                                                               \
    __syncthreads();                                                                \
    float2 tv[4];                                                                   \
    _Pragma("unroll") for (int j = 0; j < 4; j++) {                                 \
      int nl = wv * 4 + j;                                                          \
      float2 sf = bf2f((XB)[((NB) + nl) * 64 + lane]);                              \
      float inv = 1.f / (1.f + wsAcc[nl]);                                          \
      tv[j].x = (sf.x + Tacc[nl * TST + 2 * lane]) * inv;                           \
      tv[j].y = (sf.y + Tacc[nl * TST + 2 * lane + 1]) * inv;                       \
    }                                                                               \
    _Pragma("unroll") for (int j = 0; j < 4; j++) acc[j] = make_float2(0.f, 0.f);   \
    _Pragma("unroll 8") for (int k2 = 0; k2 < 64; k2++) {                           \
      float2 w0 = bf2f(Wl[lane * WST + 2 * k2]);                                    \
      float2 w1 = bf2f(Wl[lane * WST + 2 * k2 + 1]);                                \
      _Pragma("unroll") for (int j = 0; j < 4; j++) {                               \
        float bx = __shfl(tv[j].x, k2, 64);                                         \
        float by = __shfl(tv[j].y, k2, 64);                                         \
        acc[j].x += bx * w0.x + by * w1.x;                                          \
        acc[j].y += bx * w0.y + by * w1.y;                                          \
      }                                                                             \
    }                                                                               \
  }

// F: GCN layer, 16 nodes/block.
__global__ __launch_bounds__(256) void kF(const unsigned* __restrict__ xb,
                                          const int* __restrict__ colOffs,
                                          const int2* __restrict__ csrP,
                                          const float* __restrict__ W,
                                          unsigned* __restrict__ outB) {
  __shared__ unsigned Wl[128 * WST];
  __shared__ float Tacc[16 * TST];
  __shared__ float wsAcc[16];
  __shared__ int offsL[17];
  int t = threadIdx.x, lane = t & 63, wv = t >> 6;
  int nb = blockIdx.x * 16;
  const float4* W4 = (const float4*)W;
  float2 acc[4];
  LAYER_BODY(xb, nb)
#pragma unroll
  for (int j = 0; j < 4; j++) {
    int n = nb + wv * 4 + j;
    outB[n * 64 + lane] = f2bf(fmaxf(acc[j].x, 0.f), fmaxf(acc[j].y, 0.f));
  }
}

// H: layer3 + pool + final
__global__ __launch_bounds__(256) void kH(const unsigned* __restrict__ xb,
                                          const int* __restrict__ colOffs,
                                          const int2* __restrict__ csrP,
                                          const float* __restrict__ W,
                                          const float* __restrict__ Wc,
                                          float* __restrict__ gvec, unsigned* __restrict__ done,
                                          float* __restrict__ out) {
  __shared__ unsigned Wl[128 * WST];
  __shared__ float Tacc[16 * TST];
  __shared__ float wsAcc[16];
  __shared__ int offsL[17];
  __shared__ unsigned lastFlag;
  int t = threadIdx.x, lane = t & 63, wv = t >> 6;
  int nb = blockIdx.x * 16;
  const float4* W4 = (const float4*)W;
  float2 acc[4];
  LAYER_BODY(xb, nb)
  // pool: H3 never written to memory
  float s0 = 0.f, s1 = 0.f;
#pragma unroll
  for (int j = 0; j < 4; j++) {
    s0 += fmaxf(acc[j].x, 0.f);
    s1 += fmaxf(acc[j].y, 0.f);
  }
  __syncthreads();  // Tacc reads done; reuse as gpart
  float* gpart = Tacc;
  if (t < 128) gpart[t] = 0.f;
  __syncthreads();
  atomicAdd(&gpart[2 * lane], s0);
  atomicAdd(&gpart[2 * lane + 1], s1);
  __syncthreads();
  if (t < 128) atomicAdd(&gvec[t], gpart[t]);
  asm volatile("s_waitcnt vmcnt(0)" ::: "memory");  // gvec atomics complete (memory-side)
  __syncthreads();
  if (t == 0) lastFlag = (atomicAdd(done, 1u) == gridDim.x - 1) ? 1u : 0u;
  __syncthreads();
  if (lastFlag) {
    float* f0 = Tacc + 256;
    float* f1 = Tacc + 384;
    if (t < 128) {
      float gj = atomicAdd(&gvec[t], 0.f) * (1.0f / 8192.0f);  // memory-side read
      f0[t] = gj * Wc[t * 2 + 0];
      f1[t] = gj * Wc[t * 2 + 1];
    }
    __syncthreads();
    for (int o = 64; o > 0; o >>= 1) {
      if (t < o) { f0[t] += f0[t + o]; f1[t] += f1[t + o]; }
      __syncthreads();
    }
    if (t == 0) {
      float l0 = f0[0], l1 = f1[0];
      float m = fmaxf(l0, l1);
      float e0 = __expf(l0 - m), e1 = __expf(l1 - m);
      float inv = 1.f / (e0 + e1);
      out[0] = e0 * inv;
      out[1] = e1 * inv;
    }
  }
}

extern "C" void kernel_launch(void* const* d_in, const int* in_sizes, int n_in,
                              void* d_out, int out_size, void* d_ws, size_t ws_size,
                              hipStream_t stream) {
  const float* x     = (const float*)d_in[0];
  const float* embed = (const float*)d_in[1];
  const float* noise = (const float*)d_in[2];
  const float* tmp   = (const float*)d_in[3];
  const float* gat_W = (const float*)d_in[4];
  const float* att_s = (const float*)d_in[5];
  const float* att_d = (const float*)d_in[6];
  const float* gat_b = (const float*)d_in[7];
  const float* lin_W = (const float*)d_in[8];
  const float* lin_b = (const float*)d_in[9];
  const float* W1    = (const float*)d_in[10];
  const float* W2    = (const float*)d_in[11];
  const float* W3    = (const float*)d_in[12];
  const float* Wc    = (const float*)d_in[13];
  const int* ei      = (const int*)d_in[14];
  const int* nei     = (const int*)d_in[15];
  const int* row = ei;
  const int* col = ei + EE;
  const int* src2 = nei;
  const int* dst2 = nei + E2C;
  float* out = (float*)d_out;

  // workspace layout (4-byte units); 16B/8B-aligned buffers first
  char* w8 = (char*)d_ws;
  size_t off = 0;
  auto alloc = [&](size_t units) -> void* {
    void* p = w8 + off * 4;
    off += units;
    return p;
  };
  float4*   pN      = (float4*)alloc(4 * NN);
  float4*   qN      = (float4*)alloc(4 * NN);
  float2*   asz     = (float2*)alloc(2 * EE);
  int2*     csrP    = (int2*)alloc(2 * EE);
  unsigned* xb      = (unsigned*)alloc(NN * 64);
  unsigned* H1b     = (unsigned*)alloc(NN * 64);
  unsigned* H2b     = (unsigned*)alloc(NN * 64);
  float*    ad      = (float*)alloc(EE);
  int*      colCnt  = (int*)alloc(NN);
  int*      colOffs = (int*)alloc(NN + 2);
  int*      colCur  = (int*)alloc(NN);
  int*      hKeys   = (int*)alloc(HSZ);
  unsigned* hPair   = (unsigned*)alloc(HSZ);
  unsigned* bucket  = (unsigned*)alloc((size_t)NBIN * BCAP);
  unsigned* gCur    = (unsigned*)alloc(NBIN);
  float*    gvec    = (float*)alloc(128);
  unsigned* done    = (unsigned*)alloc(2);

  kA<<<512, 256, 0, stream>>>(x, embed, gat_W, att_s, att_d, lin_W, pN, qN, xb,
                              hKeys, hPair, colCnt, gvec, done, gCur);
  kB<<<EE / 256, 256, 0, stream>>>(row, col, pN, qN, asz, ad, colCnt);
  kC<<<321, 256, 0, stream>>>(src2, dst2, colCnt, colOffs, colCur, gCur, bucket);
  kD<<<NBIN, 256, 0, stream>>>(row, col, asz, ad, bucket, gCur, gat_b, lin_W,
                               lin_b, noise, tmp, hKeys, hPair);
  kE<<<EE / 256, 256, 0, stream>>>(row, col, hKeys, hPair, colCur, csrP);
  kF<<<NN / 16, 256, 0, stream>>>(xb, colOffs, csrP, W1, H1b);
  kF<<<NN / 16, 256, 0, stream>>>(H1b, colOffs, csrP, W2, H2b);
  kH<<<NN / 16, 256, 0, stream>>>(H2b, colOffs, csrP, W3, Wc, gvec, done, out);
}

// Round 10
// 248.748 us; speedup vs baseline: 1.6353x; 1.6353x over previous
//
#include <hip/hip_runtime.h>
#include <hip/hip_fp16.h>
#include <math.h>

typedef unsigned long long u64;

#define NN 8192
#define EE 81920
#define E2C 1310720
#define HSZ (1 << 18)
#define HMASK (HSZ - 1)
#define NBIN 320     // dst >> 8 : bins of 256 edge-nodes
#define BCAP 4800    // Poisson(4096), +11 sigma
#define SBITS 17     // src index bits in packed u32 payload

__device__ __forceinline__ float wsum(float v) {
#pragma unroll
  for (int m = 32; m > 0; m >>= 1) v += __shfl_xor(v, m, 64);
  return v;
}
__device__ __forceinline__ float lrelu(float x) { return x > 0.f ? x : 0.2f * x; }
__device__ __forceinline__ unsigned packh2(float a, float b) {
  __half2 h = __floats2half2_rn(a, b);
  return *reinterpret_cast<unsigned*>(&h);
}
__device__ __forceinline__ void atomic_pk_add_f16(unsigned* addr, unsigned data) {
  asm volatile("global_atomic_pk_add_f16 %0, %1, off" :: "v"(addr), "v"(data) : "memory");
}
__device__ __forceinline__ int hfind(const int* __restrict__ keys, int key) {
  unsigned i = ((unsigned)key * 2654435761u) >> 14 & HMASK;
  while (true) {
    int k = keys[i];
    if (k == key) return (int)i;
    if (k == -1) return -1;
    i = (i + 1) & HMASK;
  }
}
// bf16x2 helpers: low 16 bits = first (even-dim) element
__device__ __forceinline__ float2 bf2f(unsigned u) {
  return make_float2(__uint_as_float(u << 16), __uint_as_float(u & 0xffff0000u));
}
__device__ __forceinline__ unsigned f2bf(float a, float b) {
  unsigned ua = __float_as_uint(a);
  ua = (ua + 0x7fffu + ((ua >> 16) & 1u)) >> 16;
  unsigned ub = __float_as_uint(b);
  ub = ((ub + 0x7fffu + ((ub >> 16) & 1u)) >> 16) << 16;
  return (ua & 0xffffu) | ub;
}
// wave-uniform broadcast of lane k's value via scalar readlane (no LDS traffic)
__device__ __forceinline__ float rdlane(float v, int k) {
  return __uint_as_float(__builtin_amdgcn_readlane(__float_as_uint(v), k));
}

// A: init + x->bf16 + per-block combo in LDS + node scalars. 512 blocks.
__global__ __launch_bounds__(256) void kA(const float* __restrict__ x,
                                          const float* __restrict__ embed,
                                          const float* __restrict__ gw,
                                          const float* __restrict__ att_s,
                                          const float* __restrict__ att_d,
                                          const float* __restrict__ lin_W,
                                          float4* __restrict__ pN, float4* __restrict__ qN,
                                          unsigned* __restrict__ xb,
                                          int* __restrict__ hKeys, unsigned* __restrict__ hPair,
                                          int* __restrict__ colCnt, float* __restrict__ gvec,
                                          unsigned* __restrict__ done, unsigned* __restrict__ gCur) {
  __shared__ float sm[768];  // cA | cD | cZ
  int t = threadIdx.x, bid = blockIdx.x;
  int lane = t & 63, wv = t >> 6;
  for (int i = bid * 256 + t; i < HSZ; i += 512 * 256) { hKeys[i] = -1; hPair[i] = 0u; }
  for (int i = bid * 256 + t; i < NN; i += 512 * 256) colCnt[i] = 0;
  if (bid == 0) {
    if (t < 128) gvec[t] = 0.f;
    if (t == 0) *done = 0u;
    for (int i = t; i < NBIN; i += 256) gCur[i] = 0u;
  }
  {  // x -> bf16 (8 elems/thread)
    const float4* x4 = (const float4*)x;
    float4 a = x4[bid * 512 + t * 2];
    float4 b = x4[bid * 512 + t * 2 + 1];
    uint4 o;
    o.x = f2bf(a.x, a.y); o.y = f2bf(a.z, a.w);
    o.z = f2bf(b.x, b.y); o.w = f2bf(b.z, b.w);
    ((uint4*)xb)[bid * 256 + t] = o;
  }
  {
    float sa = 0.f, sd = 0.f, sz = 0.f;
#pragma unroll 8
    for (int k = 0; k < 64; k++) {
      float w = gw[t * 64 + k];
      sa += w * att_s[k]; sd += w * att_d[k]; sz += w * lin_W[k];
    }
    sm[t] = sa; sm[256 + t] = sd; sm[512 + t] = sz;
  }
  __syncthreads();
#pragma unroll
  for (int j = 0; j < 4; j++) {
    int n = bid * 16 + wv * 4 + j;
    float e0 = embed[n * 128 + lane], e1 = embed[n * 128 + 64 + lane];
    float pA = wsum(e0 * sm[lane] + e1 * sm[64 + lane]);
    float qA = wsum(e0 * sm[128 + lane] + e1 * sm[192 + lane]);
    float pD = wsum(e0 * sm[256 + lane] + e1 * sm[320 + lane]);
    float qD = wsum(e0 * sm[384 + lane] + e1 * sm[448 + lane]);
    float pZ = wsum(e0 * sm[512 + lane] + e1 * sm[576 + lane]);
    float qZ = wsum(e0 * sm[640 + lane] + e1 * sm[704 + lane]);
    if (lane == 0) pN[n] = make_float4(pA, pD, pZ, 0.f);
    if (lane == 1) qN[n] = make_float4(qA, qD, qZ, 0.f);
  }
}

// B: per-edge scalars + col histogram
__global__ void kB(const int* __restrict__ row, const int* __restrict__ col,
                   const float4* __restrict__ pN, const float4* __restrict__ qN,
                   float2* __restrict__ asz, float* __restrict__ ad, int* __restrict__ colCnt) {
  int e = blockIdx.x * 256 + threadIdx.x;
  int r = row[e], c = col[e];
  float4 p = pN[r];
  float4 q = qN[c];
  asz[e] = make_float2(p.x + q.x, p.z + q.z);  // {a_s, z}
  ad[e] = p.y + q.y;
  atomicAdd(&colCnt[c], 1);
}

// C: blocks 0..319 partition edge2 into 320 dst bins; block 320 scans colCnt.
__global__ __launch_bounds__(256) void kC(const int* __restrict__ src2, const int* __restrict__ dst2,
                                          const int* __restrict__ colCnt, int* __restrict__ colOffs,
                                          int* __restrict__ colCur,
                                          unsigned* __restrict__ gCur, unsigned* __restrict__ bucket) {
  int t = threadIdx.x;
  if (blockIdx.x == 320) {
    __shared__ int sd32[256];
    int beg = t * 32;
    int s = 0;
#pragma unroll 8
    for (int i = 0; i < 32; i++) s += colCnt[beg + i];
    sd32[t] = s;
    __syncthreads();
    for (int o = 1; o < 256; o <<= 1) {
      int v = (t >= o) ? sd32[t - o] : 0;
      __syncthreads();
      sd32[t] += v;
      __syncthreads();
    }
    int run = (t == 0) ? 0 : sd32[t - 1];
    for (int i = 0; i < 32; i++) {
      colOffs[beg + i] = run;
      colCur[beg + i] = run;
      run += colCnt[beg + i];
    }
    if (t == 255) colOffs[NN] = run;
    return;
  }
  __shared__ unsigned hist[NBIN], base[NBIN], lcur[NBIN];
  for (int i = t; i < NBIN; i += 256) { hist[i] = 0u; lcur[i] = 0u; }
  __syncthreads();
  int blockBase = blockIdx.x * 4096;
  int4 dv[4];
#pragma unroll
  for (int j = 0; j < 4; j++) {
    dv[j] = *(const int4*)&dst2[blockBase + j * 1024 + t * 4];
    atomicAdd(&hist[dv[j].x >> 8], 1u);
    atomicAdd(&hist[dv[j].y >> 8], 1u);
    atomicAdd(&hist[dv[j].z >> 8], 1u);
    atomicAdd(&hist[dv[j].w >> 8], 1u);
  }
  __syncthreads();
  for (int i = t; i < NBIN; i += 256)
    if (hist[i]) base[i] = atomicAdd(&gCur[i], hist[i]);
  __syncthreads();
#pragma unroll
  for (int j = 0; j < 4; j++) {
    int4 sv = *(const int4*)&src2[blockBase + j * 1024 + t * 4];
    int ss[4] = {sv.x, sv.y, sv.z, sv.w};
    int dd[4] = {dv[j].x, dv[j].y, dv[j].z, dv[j].w};
#pragma unroll
    for (int k = 0; k < 4; k++) {
      int s = ss[k], d = dd[k];
      int b = d >> 8;
      unsigned r = atomicAdd(&lcur[b], 1u);
      unsigned pos = base[b] + r;
      if (pos < BCAP) bucket[(size_t)b * BCAP + pos] = ((unsigned)(d & 255) << SBITS) | (unsigned)s;
    }
  }
}

// D: per-bin reduce (4-wide ILP) + gate + hash insert
__global__ __launch_bounds__(256) void kD(const int* __restrict__ row, const int* __restrict__ col,
                                          const float2* __restrict__ asz, const float* __restrict__ ad,
                                          const unsigned* __restrict__ bucket, const unsigned* __restrict__ gCur,
                                          const float* __restrict__ gat_b, const float* __restrict__ lin_W,
                                          const float* __restrict__ lin_b, const float* __restrict__ noise,
                                          const float* __restrict__ tmp,
                                          int* __restrict__ hKeys, unsigned* __restrict__ hPair) {
  __shared__ float acc[512];
  __shared__ float adl[256];
  int b = blockIdx.x, t = threadIdx.x, lane = t & 63;
  acc[2 * t] = 0.f; acc[2 * t + 1] = 0.f; adl[t] = ad[b * 256 + t];
  __syncthreads();
  int cnt = min((int)gCur[b], BCAP);
  const unsigned* bp = bucket + (size_t)b * BCAP;
  const unsigned SM = (1u << SBITS) - 1;
  int i = t;
  for (; i + 768 < cnt; i += 1024) {
    unsigned u0 = bp[i], u1 = bp[i + 256], u2 = bp[i + 512], u3 = bp[i + 768];
    float2 az0 = asz[u0 & SM], az1 = asz[u1 & SM], az2 = asz[u2 & SM], az3 = asz[u3 & SM];
    int l0 = u0 >> SBITS, l1 = u1 >> SBITS, l2 = u2 >> SBITS, l3 = u3 >> SBITS;
    float ea0 = __expf(lrelu(az0.x + adl[l0]));
    float ea1 = __expf(lrelu(az1.x + adl[l1]));
    float ea2 = __expf(lrelu(az2.x + adl[l2]));
    float ea3 = __expf(lrelu(az3.x + adl[l3]));
    atomicAdd(&acc[2 * l0], ea0); atomicAdd(&acc[2 * l0 + 1], ea0 * az0.y);
    atomicAdd(&acc[2 * l1], ea1); atomicAdd(&acc[2 * l1 + 1], ea1 * az1.y);
    atomicAdd(&acc[2 * l2], ea2); atomicAdd(&acc[2 * l2 + 1], ea2 * az2.y);
    atomicAdd(&acc[2 * l3], ea3); atomicAdd(&acc[2 * l3 + 1], ea3 * az3.y);
  }
  for (; i < cnt; i += 256) {
    unsigned u = bp[i];
    float2 az = asz[u & SM];
    int l = u >> SBITS;
    float ea = __expf(lrelu(az.x + adl[l]));
    atomicAdd(&acc[2 * l], ea);
    atomicAdd(&acc[2 * l + 1], ea * az.y);
  }
  __syncthreads();
  float gb = wsum(gat_b[lane] * lin_W[lane]) + lin_b[0];
  float itmp = 1.f / tmp[0];
  {
    int e = b * 256 + t;
    float2 szv = asz[e];
    float eself = __expf(lrelu(szv.x + adl[t]));
    float la = (acc[2 * t + 1] + eself * szv.y) / (acc[2 * t] + eself) + gb;
    float ns = noise[e];
    float g = (logf(ns) - log1pf(-ns) + la) * itmp;
    float gate = 1.f / (1.f + __expf(-g));
    int key = row[e] * NN + col[e];
    unsigned hi = ((unsigned)key * 2654435761u) >> 14 & HMASK;
    while (true) {
      int old = atomicCAS(&hKeys[hi], -1, key);
      if (old == -1 || old == key) break;
      hi = (hi + 1) & HMASK;
    }
    atomic_pk_add_f16(&hPair[hi], packh2(1.0f, gate));
  }
}

// E: edge_mask -> w; CSR scatter of packed (row, w)
__global__ void kE(const int* __restrict__ row, const int* __restrict__ col,
                   const int* __restrict__ hKeys, const unsigned* __restrict__ hPair,
                   int* __restrict__ colCur, int2* __restrict__ csrP) {
  int e = blockIdx.x * 256 + threadIdx.x;
  int r = row[e], c = col[e];
  int s1 = hfind(hKeys, r * NN + c);
  unsigned u1 = hPair[s1];
  __half2 h1 = *reinterpret_cast<__half2*>(&u1);
  float cv = __low2float(h1), g1 = __high2float(h1);
  int s2 = hfind(hKeys, c * NN + r);
  float g2 = 0.f;
  if (s2 >= 0) {
    unsigned u2 = hPair[s2];
    g2 = __high2float(*reinterpret_cast<__half2*>(&u2));
  }
  float em = cv * 0.5f * (g1 + g2);
  float w = 1.f / (1.f + __expf(-em));
  int pos = atomicAdd(&colCur[c], 1);
  csrP[pos] = make_int2(r, __float_as_int(w));
}

// gather one node's aggregated features (bf16 rows, 4-wide ILP); returns f32 pair
__device__ __forceinline__ float2 gatherNode(const unsigned* __restrict__ xb, int n, int lane,
                                             const int* __restrict__ colOffs,
                                             const int2* __restrict__ csrP) {
  float2 sf = bf2f(xb[n * 64 + lane]);
  float a0 = sf.x, a1 = sf.y, ws = 0.f;
  int off = colOffs[n], end = colOffs[n + 1];
  int i = off;
  for (; i + 4 <= end; i += 4) {
    int2 q0 = csrP[i], q1 = csrP[i + 1], q2 = csrP[i + 2], q3 = csrP[i + 3];
    unsigned u0 = xb[q0.x * 64 + lane];
    unsigned u1 = xb[q1.x * 64 + lane];
    unsigned u2 = xb[q2.x * 64 + lane];
    unsigned u3 = xb[q3.x * 64 + lane];
    float w0 = __int_as_float(q0.y), w1 = __int_as_float(q1.y);
    float w2 = __int_as_float(q2.y), w3 = __int_as_float(q3.y);
    ws += w0 + w1 + w2 + w3;
    float2 f0 = bf2f(u0), f1 = bf2f(u1), f2v = bf2f(u2), f3 = bf2f(u3);
    a0 += w0 * f0.x + w1 * f1.x + w2 * f2v.x + w3 * f3.x;
    a1 += w0 * f0.y + w1 * f1.y + w2 * f2v.y + w3 * f3.y;
  }
  for (; i < end; i++) {
    int2 q = csrP[i];
    unsigned u = xb[q.x * 64 + lane];
    float w = __int_as_float(q.y);
    ws += w;
    float2 f = bf2f(u);
    a0 += w * f.x;
    a1 += w * f.y;
  }
  float inv = 1.f / (1.f + ws);
  return make_float2(a0 * inv, a1 * inv);
}

// ---- GEMM: T in registers (lane L holds dims 2L,2L+1), W bf16 in 32KB LDS,
//      T[k] broadcast via scalar readlane -> only 128 ds_read_b32 per wave ----
#define GEMM2(tv, acc)                                                   \
  {                                                                      \
    _Pragma("unroll") for (int j = 0; j < 2; j++) acc[j] = make_float2(0.f, 0.f); \
    _Pragma("unroll 16") for (int k2 = 0; k2 < 64; k2++) {               \
      float2 w0 = bf2f(Wl[(2 * k2) * 64 + lane]);                        \
      float2 w1 = bf2f(Wl[(2 * k2 + 1) * 64 + lane]);                    \
      _Pragma("unroll") for (int j = 0; j < 2; j++) {                    \
        float bx = rdlane(tv[j].x, k2);                                  \
        float by = rdlane(tv[j].y, k2);                                  \
        acc[j].x += bx * w0.x + by * w1.x;                               \
        acc[j].y += bx * w0.y + by * w1.y;                               \
      }                                                                  \
    }                                                                    \
  }

// F: GCN layer, 8 nodes/block (2 per wave), LDS = 32KB -> 5 blocks/CU.
__global__ __launch_bounds__(256) void kF(const unsigned* __restrict__ xb,
                                          const int* __restrict__ colOffs,
                                          const int2* __restrict__ csrP,
                                          const float* __restrict__ W,
                                          unsigned* __restrict__ outB) {
  __shared__ unsigned Wl[128 * 64];  // bf16x2: Wl[k*64+l] = W[k][2l..2l+1]
  int t = threadIdx.x, lane = t & 63, wv = t >> 6;
  const float4* W4 = (const float4*)W;
  for (int i = t; i < 4096; i += 256) {
    float4 a = W4[i];
    ((uint2*)Wl)[i] = make_uint2(f2bf(a.x, a.y), f2bf(a.z, a.w));
  }
  int nb = blockIdx.x * 8;
  float2 tv[2];
#pragma unroll
  for (int j = 0; j < 2; j++)
    tv[j] = gatherNode(xb, nb + wv * 2 + j, lane, colOffs, csrP);
  __syncthreads();
  float2 acc[2];
  GEMM2(tv, acc)
#pragma unroll
  for (int j = 0; j < 2; j++) {
    int n = nb + wv * 2 + j;
    outB[n * 64 + lane] = f2bf(fmaxf(acc[j].x, 0.f), fmaxf(acc[j].y, 0.f));
  }
}

// H: layer3 + pool + final (done-counter; scratch folded into Wl -> LDS stays 32KB)
__global__ __launch_bounds__(256) void kH(const unsigned* __restrict__ xb,
                                          const int* __restrict__ colOffs,
                                          const int2* __restrict__ csrP,
                                          const float* __restrict__ W,
                                          const float* __restrict__ Wc,
                                          float* __restrict__ gvec, unsigned* __restrict__ done,
                                          float* __restrict__ out) {
  __shared__ unsigned Wl[128 * 64];
  int t = threadIdx.x, lane = t & 63, wv = t >> 6;
  const float4* W4 = (const float4*)W;
  for (int i = t; i < 4096; i += 256) {
    float4 a = W4[i];
    ((uint2*)Wl)[i] = make_uint2(f2bf(a.x, a.y), f2bf(a.z, a.w));
  }
  int nb = blockIdx.x * 8;
  float2 tv[2];
#pragma unroll
  for (int j = 0; j < 2; j++)
    tv[j] = gatherNode(xb, nb + wv * 2 + j, lane, colOffs, csrP);
  __syncthreads();
  float2 acc[2];
  GEMM2(tv, acc)
  // pool: H3 never written to memory
  float s0 = fmaxf(acc[0].x, 0.f) + fmaxf(acc[1].x, 0.f);
  float s1 = fmaxf(acc[0].y, 0.f) + fmaxf(acc[1].y, 0.f);
  __syncthreads();  // GEMM done reading Wl; reuse as scratch
  float* gpart = (float*)Wl;
  unsigned* flagp = (unsigned*)Wl + 600;
  if (t < 128) gpart[t] = 0.f;
  __syncthreads();
  atomicAdd(&gpart[2 * lane], s0);
  atomicAdd(&gpart[2 * lane + 1], s1);
  __syncthreads();
  if (t < 128) atomicAdd(&gvec[t], gpart[t]);
  asm volatile("s_waitcnt vmcnt(0)" ::: "memory");  // gvec atomics complete (memory-side)
  __syncthreads();
  if (t == 0) *flagp = (atomicAdd(done, 1u) == gridDim.x - 1) ? 1u : 0u;
  __syncthreads();
  if (*flagp) {
    float* f0 = (float*)Wl + 256;
    float* f1 = (float*)Wl + 384;
    if (t < 128) {
      float gj = atomicAdd(&gvec[t], 0.f) * (1.0f / 8192.0f);  // memory-side read
      f0[t] = gj * Wc[t * 2 + 0];
      f1[t] = gj * Wc[t * 2 + 1];
    }
    __syncthreads();
    for (int o = 64; o > 0; o >>= 1) {
      if (t < o) { f0[t] += f0[t + o]; f1[t] += f1[t + o]; }
      __syncthreads();
    }
    if (t == 0) {
      float l0 = f0[0], l1 = f1[0];
      float m = fmaxf(l0, l1);
      float e0 = __expf(l0 - m), e1 = __expf(l1 - m);
      float inv = 1.f / (e0 + e1);
      out[0] = e0 * inv;
      out[1] = e1 * inv;
    }
  }
}

extern "C" void kernel_launch(void* const* d_in, const int* in_sizes, int n_in,
                              void* d_out, int out_size, void* d_ws, size_t ws_size,
                              hipStream_t stream) {
  const float* x     = (const float*)d_in[0];
  const float* embed = (const float*)d_in[1];
  const float* noise = (const float*)d_in[2];
  const float* tmp   = (const float*)d_in[3];
  const float* gat_W = (const float*)d_in[4];
  const float* att_s = (const float*)d_in[5];
  const float* att_d = (const float*)d_in[6];
  const float* gat_b = (const float*)d_in[7];
  const float* lin_W = (const float*)d_in[8];
  const float* lin_b = (const float*)d_in[9];
  const float* W1    = (const float*)d_in[10];
  const float* W2    = (const float*)d_in[11];
  const float* W3    = (const float*)d_in[12];
  const float* Wc    = (const float*)d_in[13];
  const int* ei      = (const int*)d_in[14];
  const int* nei     = (const int*)d_in[15];
  const int* row = ei;
  const int* col = ei + EE;
  const int* src2 = nei;
  const int* dst2 = nei + E2C;
  float* out = (float*)d_out;

  // workspace layout (4-byte units); 16B/8B-aligned buffers first
  char* w8 = (char*)d_ws;
  size_t off = 0;
  auto alloc = [&](size_t units) -> void* {
    void* p = w8 + off * 4;
    off += units;
    return p;
  };
  float4*   pN      = (float4*)alloc(4 * NN);
  float4*   qN      = (float4*)alloc(4 * NN);
  float2*   asz     = (float2*)alloc(2 * EE);
  int2*     csrP    = (int2*)alloc(2 * EE);
  unsigned* xb      = (unsigned*)alloc(NN * 64);
  unsigned* H1b     = (unsigned*)alloc(NN * 64);
  unsigned* H2b     = (unsigned*)alloc(NN * 64);
  float*    ad      = (float*)alloc(EE);
  int*      colCnt  = (int*)alloc(NN);
  int*      colOffs = (int*)alloc(NN + 2);
  int*      colCur  = (int*)alloc(NN);
  int*      hKeys   = (int*)alloc(HSZ);
  unsigned* hPair   = (unsigned*)alloc(HSZ);
  unsigned* bucket  = (unsigned*)alloc((size_t)NBIN * BCAP);
  unsigned* gCur    = (unsigned*)alloc(NBIN);
  float*    gvec    = (float*)alloc(128);
  unsigned* done    = (unsigned*)alloc(2);

  kA<<<512, 256, 0, stream>>>(x, embed, gat_W, att_s, att_d, lin_W, pN, qN, xb,
                              hKeys, hPair, colCnt, gvec, done, gCur);
  kB<<<EE / 256, 256, 0, stream>>>(row, col, pN, qN, asz, ad, colCnt);
  kC<<<321, 256, 0, stream>>>(src2, dst2, colCnt, colOffs, colCur, gCur, bucket);
  kD<<<NBIN, 256, 0, stream>>>(row, col, asz, ad, bucket, gCur, gat_b, lin_W,
                               lin_b, noise, tmp, hKeys, hPair);
  kE<<<EE / 256, 256, 0, stream>>>(row, col, hKeys, hPair, colCur, csrP);
  kF<<<NN / 8, 256, 0, stream>>>(xb, colOffs, csrP, W1, H1b);
  kF<<<NN / 8, 256, 0, stream>>>(H1b, colOffs, csrP, W2, H2b);
  kH<<<NN / 8, 256, 0, stream>>>(H2b, colOffs, csrP, W3, Wc, gvec, done, out);
}

// Round 11
// 248.425 us; speedup vs baseline: 1.6374x; 1.0013x over previous
//
#include <hip/hip_runtime.h>
#include <hip/hip_fp16.h>
#include <math.h>

typedef unsigned long long u64;

#define NN 8192
#define EE 81920
#define E2C 1310720
#define HSZ (1 << 18)
#define HMASK (HSZ - 1)
#define NBIN 320     // dst >> 8 : bins of 256 edge-nodes
#define BCAP 4800    // Poisson(4096), +11 sigma
#define SBITS 17     // src index bits in packed u32 payload
#define ECAP 512     // staged edges per block (Poisson(80); overflow falls back to global)

__device__ __forceinline__ float wsum(float v) {
#pragma unroll
  for (int m = 32; m > 0; m >>= 1) v += __shfl_xor(v, m, 64);
  return v;
}
__device__ __forceinline__ float lrelu(float x) { return x > 0.f ? x : 0.2f * x; }
__device__ __forceinline__ unsigned packh2(float a, float b) {
  __half2 h = __floats2half2_rn(a, b);
  return *reinterpret_cast<unsigned*>(&h);
}
__device__ __forceinline__ void atomic_pk_add_f16(unsigned* addr, unsigned data) {
  asm volatile("global_atomic_pk_add_f16 %0, %1, off" :: "v"(addr), "v"(data) : "memory");
}
__device__ __forceinline__ int hfind(const int* __restrict__ keys, int key) {
  unsigned i = ((unsigned)key * 2654435761u) >> 14 & HMASK;
  while (true) {
    int k = keys[i];
    if (k == key) return (int)i;
    if (k == -1) return -1;
    i = (i + 1) & HMASK;
  }
}
// bf16x2 helpers: low 16 bits = first (even-dim) element
__device__ __forceinline__ float2 bf2f(unsigned u) {
  return make_float2(__uint_as_float(u << 16), __uint_as_float(u & 0xffff0000u));
}
__device__ __forceinline__ unsigned f2bf(float a, float b) {
  unsigned ua = __float_as_uint(a);
  ua = (ua + 0x7fffu + ((ua >> 16) & 1u)) >> 16;
  unsigned ub = __float_as_uint(b);
  ub = ((ub + 0x7fffu + ((ub >> 16) & 1u)) >> 16) << 16;
  return (ua & 0xffffu) | ub;
}
// wave-uniform broadcast of lane k's value via scalar readlane (no LDS traffic)
__device__ __forceinline__ float rdlane(float v, int k) {
  return __uint_as_float(__builtin_amdgcn_readlane(__float_as_uint(v), k));
}

// A: init + x->bf16 + per-block combo in LDS + node scalars. 512 blocks.
__global__ __launch_bounds__(256) void kA(const float* __restrict__ x,
                                          const float* __restrict__ embed,
                                          const float* __restrict__ gw,
                                          const float* __restrict__ att_s,
                                          const float* __restrict__ att_d,
                                          const float* __restrict__ lin_W,
                                          float4* __restrict__ pN, float4* __restrict__ qN,
                                          unsigned* __restrict__ xb,
                                          int* __restrict__ hKeys, unsigned* __restrict__ hPair,
                                          int* __restrict__ colCnt, float* __restrict__ gvec,
                                          unsigned* __restrict__ done, unsigned* __restrict__ gCur) {
  __shared__ float sm[768];  // cA | cD | cZ
  int t = threadIdx.x, bid = blockIdx.x;
  int lane = t & 63, wv = t >> 6;
  for (int i = bid * 256 + t; i < HSZ; i += 512 * 256) { hKeys[i] = -1; hPair[i] = 0u; }
  for (int i = bid * 256 + t; i < NN; i += 512 * 256) colCnt[i] = 0;
  if (bid == 0) {
    if (t < 128) gvec[t] = 0.f;
    if (t == 0) *done = 0u;
    for (int i = t; i < NBIN; i += 256) gCur[i] = 0u;
  }
  {  // x -> bf16 (8 elems/thread)
    const float4* x4 = (const float4*)x;
    float4 a = x4[bid * 512 + t * 2];
    float4 b = x4[bid * 512 + t * 2 + 1];
    uint4 o;
    o.x = f2bf(a.x, a.y); o.y = f2bf(a.z, a.w);
    o.z = f2bf(b.x, b.y); o.w = f2bf(b.z, b.w);
    ((uint4*)xb)[bid * 256 + t] = o;
  }
  {
    float sa = 0.f, sd = 0.f, sz = 0.f;
#pragma unroll 8
    for (int k = 0; k < 64; k++) {
      float w = gw[t * 64 + k];
      sa += w * att_s[k]; sd += w * att_d[k]; sz += w * lin_W[k];
    }
    sm[t] = sa; sm[256 + t] = sd; sm[512 + t] = sz;
  }
  __syncthreads();
#pragma unroll
  for (int j = 0; j < 4; j++) {
    int n = bid * 16 + wv * 4 + j;
    float e0 = embed[n * 128 + lane], e1 = embed[n * 128 + 64 + lane];
    float pA = wsum(e0 * sm[lane] + e1 * sm[64 + lane]);
    float qA = wsum(e0 * sm[128 + lane] + e1 * sm[192 + lane]);
    float pD = wsum(e0 * sm[256 + lane] + e1 * sm[320 + lane]);
    float qD = wsum(e0 * sm[384 + lane] + e1 * sm[448 + lane]);
    float pZ = wsum(e0 * sm[512 + lane] + e1 * sm[576 + lane]);
    float qZ = wsum(e0 * sm[640 + lane] + e1 * sm[704 + lane]);
    if (lane == 0) pN[n] = make_float4(pA, pD, pZ, 0.f);
    if (lane == 1) qN[n] = make_float4(qA, qD, qZ, 0.f);
  }
}

// B: per-edge scalars + col histogram
__global__ void kB(const int* __restrict__ row, const int* __restrict__ col,
                   const float4* __restrict__ pN, const float4* __restrict__ qN,
                   float2* __restrict__ asz, float* __restrict__ ad, int* __restrict__ colCnt) {
  int e = blockIdx.x * 256 + threadIdx.x;
  int r = row[e], c = col[e];
  float4 p = pN[r];
  float4 q = qN[c];
  asz[e] = make_float2(p.x + q.x, p.z + q.z);  // {a_s, z}
  ad[e] = p.y + q.y;
  atomicAdd(&colCnt[c], 1);
}

// C: blocks 0..319 partition edge2 into 320 dst bins; block 320 scans colCnt.
__global__ __launch_bounds__(256) void kC(const int* __restrict__ src2, const int* __restrict__ dst2,
                                          const int* __restrict__ colCnt, int* __restrict__ colOffs,
                                          int* __restrict__ colCur,
                                          unsigned* __restrict__ gCur, unsigned* __restrict__ bucket) {
  int t = threadIdx.x;
  if (blockIdx.x == 320) {
    __shared__ int sd32[256];
    int beg = t * 32;
    int s = 0;
#pragma unroll 8
    for (int i = 0; i < 32; i++) s += colCnt[beg + i];
    sd32[t] = s;
    __syncthreads();
    for (int o = 1; o < 256; o <<= 1) {
      int v = (t >= o) ? sd32[t - o] : 0;
      __syncthreads();
      sd32[t] += v;
      __syncthreads();
    }
    int run = (t == 0) ? 0 : sd32[t - 1];
    for (int i = 0; i < 32; i++) {
      colOffs[beg + i] = run;
      colCur[beg + i] = run;
      run += colCnt[beg + i];
    }
    if (t == 255) colOffs[NN] = run;
    return;
  }
  __shared__ unsigned hist[NBIN], base[NBIN], lcur[NBIN];
  for (int i = t; i < NBIN; i += 256) { hist[i] = 0u; lcur[i] = 0u; }
  __syncthreads();
  int blockBase = blockIdx.x * 4096;
  int4 dv[4];
#pragma unroll
  for (int j = 0; j < 4; j++) {
    dv[j] = *(const int4*)&dst2[blockBase + j * 1024 + t * 4];
    atomicAdd(&hist[dv[j].x >> 8], 1u);
    atomicAdd(&hist[dv[j].y >> 8], 1u);
    atomicAdd(&hist[dv[j].z >> 8], 1u);
    atomicAdd(&hist[dv[j].w >> 8], 1u);
  }
  __syncthreads();
  for (int i = t; i < NBIN; i += 256)
    if (hist[i]) base[i] = atomicAdd(&gCur[i], hist[i]);
  __syncthreads();
#pragma unroll
  for (int j = 0; j < 4; j++) {
    int4 sv = *(const int4*)&src2[blockBase + j * 1024 + t * 4];
    int ss[4] = {sv.x, sv.y, sv.z, sv.w};
    int dd[4] = {dv[j].x, dv[j].y, dv[j].z, dv[j].w};
#pragma unroll
    for (int k = 0; k < 4; k++) {
      int s = ss[k], d = dd[k];
      int b = d >> 8;
      unsigned r = atomicAdd(&lcur[b], 1u);
      unsigned pos = base[b] + r;
      if (pos < BCAP) bucket[(size_t)b * BCAP + pos] = ((unsigned)(d & 255) << SBITS) | (unsigned)s;
    }
  }
}

// D: per-bin reduce (4-wide ILP) + gate + hash insert
__global__ __launch_bounds__(256) void kD(const int* __restrict__ row, const int* __restrict__ col,
                                          const float2* __restrict__ asz, const float* __restrict__ ad,
                                          const unsigned* __restrict__ bucket, const unsigned* __restrict__ gCur,
                                          const float* __restrict__ gat_b, const float* __restrict__ lin_W,
                                          const float* __restrict__ lin_b, const float* __restrict__ noise,
                                          const float* __restrict__ tmp,
                                          int* __restrict__ hKeys, unsigned* __restrict__ hPair) {
  __shared__ float acc[512];
  __shared__ float adl[256];
  int b = blockIdx.x, t = threadIdx.x, lane = t & 63;
  acc[2 * t] = 0.f; acc[2 * t + 1] = 0.f; adl[t] = ad[b * 256 + t];
  __syncthreads();
  int cnt = min((int)gCur[b], BCAP);
  const unsigned* bp = bucket + (size_t)b * BCAP;
  const unsigned SM = (1u << SBITS) - 1;
  int i = t;
  for (; i + 768 < cnt; i += 1024) {
    unsigned u0 = bp[i], u1 = bp[i + 256], u2 = bp[i + 512], u3 = bp[i + 768];
    float2 az0 = asz[u0 & SM], az1 = asz[u1 & SM], az2 = asz[u2 & SM], az3 = asz[u3 & SM];
    int l0 = u0 >> SBITS, l1 = u1 >> SBITS, l2 = u2 >> SBITS, l3 = u3 >> SBITS;
    float ea0 = __expf(lrelu(az0.x + adl[l0]));
    float ea1 = __expf(lrelu(az1.x + adl[l1]));
    float ea2 = __expf(lrelu(az2.x + adl[l2]));
    float ea3 = __expf(lrelu(az3.x + adl[l3]));
    atomicAdd(&acc[2 * l0], ea0); atomicAdd(&acc[2 * l0 + 1], ea0 * az0.y);
    atomicAdd(&acc[2 * l1], ea1); atomicAdd(&acc[2 * l1 + 1], ea1 * az1.y);
    atomicAdd(&acc[2 * l2], ea2); atomicAdd(&acc[2 * l2 + 1], ea2 * az2.y);
    atomicAdd(&acc[2 * l3], ea3); atomicAdd(&acc[2 * l3 + 1], ea3 * az3.y);
  }
  for (; i < cnt; i += 256) {
    unsigned u = bp[i];
    float2 az = asz[u & SM];
    int l = u >> SBITS;
    float ea = __expf(lrelu(az.x + adl[l]));
    atomicAdd(&acc[2 * l], ea);
    atomicAdd(&acc[2 * l + 1], ea * az.y);
  }
  __syncthreads();
  float gb = wsum(gat_b[lane] * lin_W[lane]) + lin_b[0];
  float itmp = 1.f / tmp[0];
  {
    int e = b * 256 + t;
    float2 szv = asz[e];
    float eself = __expf(lrelu(szv.x + adl[t]));
    float la = (acc[2 * t + 1] + eself * szv.y) / (acc[2 * t] + eself) + gb;
    float ns = noise[e];
    float g = (logf(ns) - log1pf(-ns) + la) * itmp;
    float gate = 1.f / (1.f + __expf(-g));
    int key = row[e] * NN + col[e];
    unsigned hi = ((unsigned)key * 2654435761u) >> 14 & HMASK;
    while (true) {
      int old = atomicCAS(&hKeys[hi], -1, key);
      if (old == -1 || old == key) break;
      hi = (hi + 1) & HMASK;
    }
    atomic_pk_add_f16(&hPair[hi], packh2(1.0f, gate));
  }
}

// E: edge_mask -> w; CSR scatter of packed (row, w)
__global__ void kE(const int* __restrict__ row, const int* __restrict__ col,
                   const int* __restrict__ hKeys, const unsigned* __restrict__ hPair,
                   int* __restrict__ colCur, int2* __restrict__ csrP) {
  int e = blockIdx.x * 256 + threadIdx.x;
  int r = row[e], c = col[e];
  int s1 = hfind(hKeys, r * NN + c);
  unsigned u1 = hPair[s1];
  __half2 h1 = *reinterpret_cast<__half2*>(&u1);
  float cv = __low2float(h1), g1 = __high2float(h1);
  int s2 = hfind(hKeys, c * NN + r);
  float g2 = 0.f;
  if (s2 >= 0) {
    unsigned u2 = hPair[s2];
    g2 = __high2float(*reinterpret_cast<__half2*>(&u2));
  }
  float em = cv * 0.5f * (g1 + g2);
  float w = 1.f / (1.f + __expf(-em));
  int pos = atomicAdd(&colCur[c], 1);
  csrP[pos] = make_int2(r, __float_as_int(w));
}

// ---- GEMM: T in registers (lane L holds dims 2L,2L+1), W bf16 in 32KB LDS,
//      T[k] broadcast via scalar readlane -> only 128 ds_read_b32 per wave ----
#define GEMM2(tv, acc)                                                   \
  {                                                                      \
    _Pragma("unroll") for (int j = 0; j < 2; j++) acc[j] = make_float2(0.f, 0.f); \
    _Pragma("unroll 16") for (int k2 = 0; k2 < 64; k2++) {               \
      float2 w0 = bf2f(Wl[(2 * k2) * 64 + lane]);                        \
      float2 w1 = bf2f(Wl[(2 * k2 + 1) * 64 + lane]);                    \
      _Pragma("unroll") for (int j = 0; j < 2; j++) {                    \
        float bx = rdlane(tv[j].x, k2);                                  \
        float by = rdlane(tv[j].y, k2);                                  \
        acc[j].x += bx * w0.x + by * w1.x;                               \
        acc[j].y += bx * w0.y + by * w1.y;                               \
      }                                                                  \
    }                                                                    \
  }

// ---- layer prologue: stage W(bf16) + block edge list into LDS, then gather with
//      8-wide independent xb loads (addresses from LDS -> single-level VMEM chain) ----
#define LAYER_GATHER(XB)                                                          \
  {                                                                               \
    const float4* W4 = (const float4*)W;                                          \
    for (int i = t; i < 4096; i += 256) {                                         \
      float4 a = W4[i];                                                           \
      ((uint2*)Wl)[i] = make_uint2(f2bf(a.x, a.y), f2bf(a.z, a.w));               \
    }                                                                             \
    if (t < 9) offsL[t] = colOffs[nb + t];                                        \
    __syncthreads();                                                              \
    int beg0 = offsL[0], cntE = offsL[8] - beg0;                                  \
    for (int i = t; i < cntE && i < ECAP; i += 256) eL[i] = csrP[beg0 + i];       \
    __syncthreads();                                                              \
    _Pragma("unroll") for (int j = 0; j < 2; j++) {                               \
      int n = nb + wv * 2 + j;                                                    \
      int off = offsL[wv * 2 + j] - beg0, end = offsL[wv * 2 + j + 1] - beg0;     \
      float2 sf = bf2f((XB)[n * 64 + lane]);                                      \
      float a0 = sf.x, a1 = sf.y, ws = 0.f;                                       \
      int i = off;                                                                \
      for (; i + 8 <= end; i += 8) {                                              \
        int2 q[8];                                                                \
        unsigned u[8];                                                            \
        if (i + 8 <= ECAP) {                                                      \
          _Pragma("unroll") for (int k = 0; k < 8; k++) q[k] = eL[i + k];         \
        } else {                                                                  \
          _Pragma("unroll") for (int k = 0; k < 8; k++) q[k] = csrP[beg0 + i + k];\
        }                                                                         \
        _Pragma("unroll") for (int k = 0; k < 8; k++) u[k] = (XB)[q[k].x * 64 + lane]; \
        _Pragma("unroll") for (int k = 0; k < 8; k++) {                           \
          float w = __int_as_float(q[k].y);                                       \
          float2 f = bf2f(u[k]);                                                  \
          ws += w; a0 += w * f.x; a1 += w * f.y;                                  \
        }                                                                         \
      }                                                                           \
      for (; i < end; i++) {                                                      \
        int2 q = (i < ECAP) ? eL[i] : csrP[beg0 + i];                             \
        unsigned u = (XB)[q.x * 64 + lane];                                       \
        float w = __int_as_float(q.y);                                            \
        float2 f = bf2f(u);                                                       \
        ws += w; a0 += w * f.x; a1 += w * f.y;                                    \
      }                                                                           \
      float inv = 1.f / (1.f + ws);                                               \
      tv[j] = make_float2(a0 * inv, a1 * inv);                                    \
    }                                                                             \
  }

// F: GCN layer, 8 nodes/block (2 per wave), LDS ~37KB -> 4 blocks/CU.
__global__ __launch_bounds__(256) void kF(const unsigned* __restrict__ xb,
                                          const int* __restrict__ colOffs,
                                          const int2* __restrict__ csrP,
                                          const float* __restrict__ W,
                                          unsigned* __restrict__ outB) {
  __shared__ unsigned Wl[128 * 64];  // bf16x2: Wl[k*64+l] = W[k][2l..2l+1]
  __shared__ int2 eL[ECAP];
  __shared__ int offsL[9];
  int t = threadIdx.x, lane = t & 63, wv = t >> 6;
  int nb = blockIdx.x * 8;
  float2 tv[2];
  LAYER_GATHER(xb)
  float2 acc[2];
  GEMM2(tv, acc)
#pragma unroll
  for (int j = 0; j < 2; j++) {
    int n = nb + wv * 2 + j;
    outB[n * 64 + lane] = f2bf(fmaxf(acc[j].x, 0.f), fmaxf(acc[j].y, 0.f));
  }
}

// H: layer3 + pool + final (done-counter; scratch folded into eL region)
__global__ __launch_bounds__(256) void kH(const unsigned* __restrict__ xb,
                                          const int* __restrict__ colOffs,
                                          const int2* __restrict__ csrP,
                                          const float* __restrict__ W,
                                          const float* __restrict__ Wc,
                                          float* __restrict__ gvec, unsigned* __restrict__ done,
                                          float* __restrict__ out) {
  __shared__ unsigned Wl[128 * 64];
  __shared__ int2 eL[ECAP];
  __shared__ int offsL[9];
  int t = threadIdx.x, lane = t & 63, wv = t >> 6;
  int nb = blockIdx.x * 8;
  float2 tv[2];
  LAYER_GATHER(xb)
  float2 acc[2];
  GEMM2(tv, acc)
  // pool: H3 never written to memory
  float s0 = fmaxf(acc[0].x, 0.f) + fmaxf(acc[1].x, 0.f);
  float s1 = fmaxf(acc[0].y, 0.f) + fmaxf(acc[1].y, 0.f);
  __syncthreads();  // gather/GEMM done; reuse eL as scratch
  float* gpart = (float*)eL;
  unsigned* flagp = (unsigned*)eL + 600;
  if (t < 128) gpart[t] = 0.f;
  __syncthreads();
  atomicAdd(&gpart[2 * lane], s0);
  atomicAdd(&gpart[2 * lane + 1], s1);
  __syncthreads();
  if (t < 128) atomicAdd(&gvec[t], gpart[t]);
  asm volatile("s_waitcnt vmcnt(0)" ::: "memory");  // gvec atomics complete (memory-side)
  __syncthreads();
  if (t == 0) *flagp = (atomicAdd(done, 1u) == gridDim.x - 1) ? 1u : 0u;
  __syncthreads();
  if (*flagp) {
    float* f0 = (float*)eL + 256;
    float* f1 = (float*)eL + 384;
    if (t < 128) {
      float gj = atomicAdd(&gvec[t], 0.f) * (1.0f / 8192.0f);  // memory-side read
      f0[t] = gj * Wc[t * 2 + 0];
      f1[t] = gj * Wc[t * 2 + 1];
    }
    __syncthreads();
    for (int o = 64; o > 0; o >>= 1) {
      if (t < o) { f0[t] += f0[t + o]; f1[t] += f1[t + o]; }
      __syncthreads();
    }
    if (t == 0) {
      float l0 = f0[0], l1 = f1[0];
      float m = fmaxf(l0, l1);
      float e0 = __expf(l0 - m), e1 = __expf(l1 - m);
      float inv = 1.f / (e0 + e1);
      out[0] = e0 * inv;
      out[1] = e1 * inv;
    }
  }
}

extern "C" void kernel_launch(void* const* d_in, const int* in_sizes, int n_in,
                              void* d_out, int out_size, void* d_ws, size_t ws_size,
                              hipStream_t stream) {
  const float* x     = (const float*)d_in[0];
  const float* embed = (const float*)d_in[1];
  const float* noise = (const float*)d_in[2];
  const float* tmp   = (const float*)d_in[3];
  const float* gat_W = (const float*)d_in[4];
  const float* att_s = (const float*)d_in[5];
  const float* att_d = (const float*)d_in[6];
  const float* gat_b = (const float*)d_in[7];
  const float* lin_W = (const float*)d_in[8];
  const float* lin_b = (const float*)d_in[9];
  const float* W1    = (const float*)d_in[10];
  const float* W2    = (const float*)d_in[11];
  const float* W3    = (const float*)d_in[12];
  const float* Wc    = (const float*)d_in[13];
  const int* ei      = (const int*)d_in[14];
  const int* nei     = (const int*)d_in[15];
  const int* row = ei;
  const int* col = ei + EE;
  const int* src2 = nei;
  const int* dst2 = nei + E2C;
  float* out = (float*)d_out;

  // workspace layout (4-byte units); 16B/8B-aligned buffers first
  char* w8 = (char*)d_ws;
  size_t off = 0;
  auto alloc = [&](size_t units) -> void* {
    void* p = w8 + off * 4;
    off += units;
    return p;
  };
  float4*   pN      = (float4*)alloc(4 * NN);
  float4*   qN      = (float4*)alloc(4 * NN);
  float2*   asz     = (float2*)alloc(2 * EE);
  int2*     csrP    = (int2*)alloc(2 * EE);
  unsigned* xb      = (unsigned*)alloc(NN * 64);
  unsigned* H1b     = (unsigned*)alloc(NN * 64);
  unsigned* H2b     = (unsigned*)alloc(NN * 64);
  float*    ad      = (float*)alloc(EE);
  int*      colCnt  = (int*)alloc(NN);
  int*      colOffs = (int*)alloc(NN + 2);
  int*      colCur  = (int*)alloc(NN);
  int*      hKeys   = (int*)alloc(HSZ);
  unsigned* hPair   = (unsigned*)alloc(HSZ);
  unsigned* bucket  = (unsigned*)alloc((size_t)NBIN * BCAP);
  unsigned* gCur    = (unsigned*)alloc(NBIN);
  float*    gvec    = (float*)alloc(128);
  unsigned* done    = (unsigned*)alloc(2);

  kA<<<512, 256, 0, stream>>>(x, embed, gat_W, att_s, att_d, lin_W, pN, qN, xb,
                              hKeys, hPair, colCnt, gvec, done, gCur);
  kB<<<EE / 256, 256, 0, stream>>>(row, col, pN, qN, asz, ad, colCnt);
  kC<<<321, 256, 0, stream>>>(src2, dst2, colCnt, colOffs, colCur, gCur, bucket);
  kD<<<NBIN, 256, 0, stream>>>(row, col, asz, ad, bucket, gCur, gat_b, lin_W,
                               lin_b, noise, tmp, hKeys, hPair);
  kE<<<EE / 256, 256, 0, stream>>>(row, col, hKeys, hPair, colCur, csrP);
  kF<<<NN / 8, 256, 0, stream>>>(xb, colOffs, csrP, W1, H1b);
  kF<<<NN / 8, 256, 0, stream>>>(H1b, colOffs, csrP, W2, H2b);
  kH<<<NN / 8, 256, 0, stream>>>(H2b, colOffs, csrP, W3, Wc, gvec, done, out);
}

// Round 12
// 229.090 us; speedup vs baseline: 1.7756x; 1.0844x over previous
//
#include <hip/hip_runtime.h>
#include <hip/hip_fp16.h>
#include <math.h>

typedef unsigned long long u64;

#define NN 8192
#define EE 81920
#define E2C 1310720
#define HSZ (1 << 18)
#define HMASK (HSZ - 1)
#define NBIN 320     // dst >> 8 : bins of 256 edge-nodes
#define BCAP 4800    // Poisson(4096), +11 sigma
#define SBITS 17     // src index bits in packed u32 payload

__device__ __forceinline__ float wsum(float v) {
#pragma unroll
  for (int m = 32; m > 0; m >>= 1) v += __shfl_xor(v, m, 64);
  return v;
}
__device__ __forceinline__ float lrelu(float x) { return x > 0.f ? x : 0.2f * x; }
__device__ __forceinline__ unsigned packh2(float a, float b) {
  __half2 h = __floats2half2_rn(a, b);
  return *reinterpret_cast<unsigned*>(&h);
}
__device__ __forceinline__ void atomic_pk_add_f16(unsigned* addr, unsigned data) {
  asm volatile("global_atomic_pk_add_f16 %0, %1, off" :: "v"(addr), "v"(data) : "memory");
}
__device__ __forceinline__ int hfind(const int* __restrict__ keys, int key) {
  unsigned i = ((unsigned)key * 2654435761u) >> 14 & HMASK;
  while (true) {
    int k = keys[i];
    if (k == key) return (int)i;
    if (k == -1) return -1;
    i = (i + 1) & HMASK;
  }
}
// bf16x2 helpers: low 16 bits = first (even-dim) element
__device__ __forceinline__ float2 bf2f(unsigned u) {
  return make_float2(__uint_as_float(u << 16), __uint_as_float(u & 0xffff0000u));
}
__device__ __forceinline__ unsigned f2bf(float a, float b) {
  unsigned ua = __float_as_uint(a);
  ua = (ua + 0x7fffu + ((ua >> 16) & 1u)) >> 16;
  unsigned ub = __float_as_uint(b);
  ub = ((ub + 0x7fffu + ((ub >> 16) & 1u)) >> 16) << 16;
  return (ua & 0xffffu) | ub;
}
// wave-uniform broadcast of lane k's value via scalar readlane (no LDS traffic)
__device__ __forceinline__ float rdlane(float v, int k) {
  return __uint_as_float(__builtin_amdgcn_readlane(__float_as_uint(v), k));
}

// A: init + x->bf16 + per-block combo in LDS + node scalars. 512 blocks.
__global__ __launch_bounds__(256) void kA(const float* __restrict__ x,
                                          const float* __restrict__ embed,
                                          const float* __restrict__ gw,
                                          const float* __restrict__ att_s,
                                          const float* __restrict__ att_d,
                                          const float* __restrict__ lin_W,
                                          float4* __restrict__ pN, float4* __restrict__ qN,
                                          unsigned* __restrict__ xb,
                                          int* __restrict__ hKeys, unsigned* __restrict__ hPair,
                                          int* __restrict__ colCnt, float* __restrict__ gvec,
                                          unsigned* __restrict__ done, unsigned* __restrict__ gCur) {
  __shared__ float sm[768];  // cA | cD | cZ
  int t = threadIdx.x, bid = blockIdx.x;
  int lane = t & 63, wv = t >> 6;
  for (int i = bid * 256 + t; i < HSZ; i += 512 * 256) { hKeys[i] = -1; hPair[i] = 0u; }
  for (int i = bid * 256 + t; i < NN; i += 512 * 256) colCnt[i] = 0;
  if (bid == 0) {
    for (int i = t; i < 2048; i += 256) gvec[i] = 0.f;  // 16 contention-spread copies
    if (t == 0) *done = 0u;
    for (int i = t; i < NBIN; i += 256) gCur[i] = 0u;
  }
  {  // x -> bf16 (8 elems/thread)
    const float4* x4 = (const float4*)x;
    float4 a = x4[bid * 512 + t * 2];
    float4 b = x4[bid * 512 + t * 2 + 1];
    uint4 o;
    o.x = f2bf(a.x, a.y); o.y = f2bf(a.z, a.w);
    o.z = f2bf(b.x, b.y); o.w = f2bf(b.z, b.w);
    ((uint4*)xb)[bid * 256 + t] = o;
  }
  {
    float sa = 0.f, sd = 0.f, sz = 0.f;
#pragma unroll 8
    for (int k = 0; k < 64; k++) {
      float w = gw[t * 64 + k];
      sa += w * att_s[k]; sd += w * att_d[k]; sz += w * lin_W[k];
    }
    sm[t] = sa; sm[256 + t] = sd; sm[512 + t] = sz;
  }
  __syncthreads();
#pragma unroll
  for (int j = 0; j < 4; j++) {
    int n = bid * 16 + wv * 4 + j;
    float e0 = embed[n * 128 + lane], e1 = embed[n * 128 + 64 + lane];
    float pA = wsum(e0 * sm[lane] + e1 * sm[64 + lane]);
    float qA = wsum(e0 * sm[128 + lane] + e1 * sm[192 + lane]);
    float pD = wsum(e0 * sm[256 + lane] + e1 * sm[320 + lane]);
    float qD = wsum(e0 * sm[384 + lane] + e1 * sm[448 + lane]);
    float pZ = wsum(e0 * sm[512 + lane] + e1 * sm[576 + lane]);
    float qZ = wsum(e0 * sm[640 + lane] + e1 * sm[704 + lane]);
    if (lane == 0) pN[n] = make_float4(pA, pD, pZ, 0.f);
    if (lane == 1) qN[n] = make_float4(qA, qD, qZ, 0.f);
  }
}

// B: per-edge scalars + col histogram
__global__ void kB(const int* __restrict__ row, const int* __restrict__ col,
                   const float4* __restrict__ pN, const float4* __restrict__ qN,
                   float2* __restrict__ asz, float* __restrict__ ad, int* __restrict__ colCnt) {
  int e = blockIdx.x * 256 + threadIdx.x;
  int r = row[e], c = col[e];
  float4 p = pN[r];
  float4 q = qN[c];
  asz[e] = make_float2(p.x + q.x, p.z + q.z);  // {a_s, z}
  ad[e] = p.y + q.y;
  atomicAdd(&colCnt[c], 1);
}

// C: blocks 0..319 partition edge2 into 320 dst bins; block 320 scans colCnt.
__global__ __launch_bounds__(256) void kC(const int* __restrict__ src2, const int* __restrict__ dst2,
                                          const int* __restrict__ colCnt, int* __restrict__ colOffs,
                                          int* __restrict__ colCur,
                                          unsigned* __restrict__ gCur, unsigned* __restrict__ bucket) {
  int t = threadIdx.x;
  if (blockIdx.x == 320) {
    __shared__ int sd32[256];
    int beg = t * 32;
    int s = 0;
#pragma unroll 8
    for (int i = 0; i < 32; i++) s += colCnt[beg + i];
    sd32[t] = s;
    __syncthreads();
    for (int o = 1; o < 256; o <<= 1) {
      int v = (t >= o) ? sd32[t - o] : 0;
      __syncthreads();
      sd32[t] += v;
      __syncthreads();
    }
    int run = (t == 0) ? 0 : sd32[t - 1];
    for (int i = 0; i < 32; i++) {
      colOffs[beg + i] = run;
      colCur[beg + i] = run;
      run += colCnt[beg + i];
    }
    if (t == 255) colOffs[NN] = run;
    return;
  }
  __shared__ unsigned hist[NBIN], base[NBIN], lcur[NBIN];
  for (int i = t; i < NBIN; i += 256) { hist[i] = 0u; lcur[i] = 0u; }
  __syncthreads();
  int blockBase = blockIdx.x * 4096;
  int4 dv[4];
#pragma unroll
  for (int j = 0; j < 4; j++) {
    dv[j] = *(const int4*)&dst2[blockBase + j * 1024 + t * 4];
    atomicAdd(&hist[dv[j].x >> 8], 1u);
    atomicAdd(&hist[dv[j].y >> 8], 1u);
    atomicAdd(&hist[dv[j].z >> 8], 1u);
    atomicAdd(&hist[dv[j].w >> 8], 1u);
  }
  __syncthreads();
  for (int i = t; i < NBIN; i += 256)
    if (hist[i]) base[i] = atomicAdd(&gCur[i], hist[i]);
  __syncthreads();
#pragma unroll
  for (int j = 0; j < 4; j++) {
    int4 sv = *(const int4*)&src2[blockBase + j * 1024 + t * 4];
    int ss[4] = {sv.x, sv.y, sv.z, sv.w};
    int dd[4] = {dv[j].x, dv[j].y, dv[j].z, dv[j].w};
#pragma unroll
    for (int k = 0; k < 4; k++) {
      int s = ss[k], d = dd[k];
      int b = d >> 8;
      unsigned r = atomicAdd(&lcur[b], 1u);
      unsigned pos = base[b] + r;
      if (pos < BCAP) bucket[(size_t)b * BCAP + pos] = ((unsigned)(d & 255) << SBITS) | (unsigned)s;
    }
  }
}

// D: per-bin reduce (4-wide ILP) + gate + hash insert
__global__ __launch_bounds__(256) void kD(const int* __restrict__ row, const int* __restrict__ col,
                                          const float2* __restrict__ asz, const float* __restrict__ ad,
                                          const unsigned* __restrict__ bucket, const unsigned* __restrict__ gCur,
                                          const float* __restrict__ gat_b, const float* __restrict__ lin_W,
                                          const float* __restrict__ lin_b, const float* __restrict__ noise,
                                          const float* __restrict__ tmp,
                                          int* __restrict__ hKeys, unsigned* __restrict__ hPair) {
  __shared__ float acc[512];
  __shared__ float adl[256];
  int b = blockIdx.x, t = threadIdx.x, lane = t & 63;
  acc[2 * t] = 0.f; acc[2 * t + 1] = 0.f; adl[t] = ad[b * 256 + t];
  __syncthreads();
  int cnt = min((int)gCur[b], BCAP);
  const unsigned* bp = bucket + (size_t)b * BCAP;
  const unsigned SM = (1u << SBITS) - 1;
  int i = t;
  for (; i + 768 < cnt; i += 1024) {
    unsigned u0 = bp[i], u1 = bp[i + 256], u2 = bp[i + 512], u3 = bp[i + 768];
    float2 az0 = asz[u0 & SM], az1 = asz[u1 & SM], az2 = asz[u2 & SM], az3 = asz[u3 & SM];
    int l0 = u0 >> SBITS, l1 = u1 >> SBITS, l2 = u2 >> SBITS, l3 = u3 >> SBITS;
    float ea0 = __expf(lrelu(az0.x + adl[l0]));
    float ea1 = __expf(lrelu(az1.x + adl[l1]));
    float ea2 = __expf(lrelu(az2.x + adl[l2]));
    float ea3 = __expf(lrelu(az3.x + adl[l3]));
    atomicAdd(&acc[2 * l0], ea0); atomicAdd(&acc[2 * l0 + 1], ea0 * az0.y);
    atomicAdd(&acc[2 * l1], ea1); atomicAdd(&acc[2 * l1 + 1], ea1 * az1.y);
    atomicAdd(&acc[2 * l2], ea2); atomicAdd(&acc[2 * l2 + 1], ea2 * az2.y);
    atomicAdd(&acc[2 * l3], ea3); atomicAdd(&acc[2 * l3 + 1], ea3 * az3.y);
  }
  for (; i < cnt; i += 256) {
    unsigned u = bp[i];
    float2 az = asz[u & SM];
    int l = u >> SBITS;
    float ea = __expf(lrelu(az.x + adl[l]));
    atomicAdd(&acc[2 * l], ea);
    atomicAdd(&acc[2 * l + 1], ea * az.y);
  }
  __syncthreads();
  float gb = wsum(gat_b[lane] * lin_W[lane]) + lin_b[0];
  float itmp = 1.f / tmp[0];
  {
    int e = b * 256 + t;
    float2 szv = asz[e];
    float eself = __expf(lrelu(szv.x + adl[t]));
    float la = (acc[2 * t + 1] + eself * szv.y) / (acc[2 * t] + eself) + gb;
    float ns = noise[e];
    float g = (logf(ns) - log1pf(-ns) + la) * itmp;
    float gate = 1.f / (1.f + __expf(-g));
    int key = row[e] * NN + col[e];
    unsigned hi = ((unsigned)key * 2654435761u) >> 14 & HMASK;
    while (true) {
      int old = atomicCAS(&hKeys[hi], -1, key);
      if (old == -1 || old == key) break;
      hi = (hi + 1) & HMASK;
    }
    atomic_pk_add_f16(&hPair[hi], packh2(1.0f, gate));
  }
}

// E: edge_mask -> w; CSR scatter of packed (row, w)
__global__ void kE(const int* __restrict__ row, const int* __restrict__ col,
                   const int* __restrict__ hKeys, const unsigned* __restrict__ hPair,
                   int* __restrict__ colCur, int2* __restrict__ csrP) {
  int e = blockIdx.x * 256 + threadIdx.x;
  int r = row[e], c = col[e];
  int s1 = hfind(hKeys, r * NN + c);
  unsigned u1 = hPair[s1];
  __half2 h1 = *reinterpret_cast<__half2*>(&u1);
  float cv = __low2float(h1), g1 = __high2float(h1);
  int s2 = hfind(hKeys, c * NN + r);
  float g2 = 0.f;
  if (s2 >= 0) {
    unsigned u2 = hPair[s2];
    g2 = __high2float(*reinterpret_cast<__half2*>(&u2));
  }
  float em = cv * 0.5f * (g1 + g2);
  float w = 1.f / (1.f + __expf(-em));
  int pos = atomicAdd(&colCur[c], 1);
  csrP[pos] = make_int2(r, __float_as_int(w));
}

// gather one node's aggregated features (bf16 rows, 4-wide ILP); returns f32 pair
__device__ __forceinline__ float2 gatherNode(const unsigned* __restrict__ xb, int n, int lane,
                                             const int* __restrict__ colOffs,
                                             const int2* __restrict__ csrP) {
  float2 sf = bf2f(xb[n * 64 + lane]);
  float a0 = sf.x, a1 = sf.y, ws = 0.f;
  int off = colOffs[n], end = colOffs[n + 1];
  int i = off;
  for (; i + 4 <= end; i += 4) {
    int2 q0 = csrP[i], q1 = csrP[i + 1], q2 = csrP[i + 2], q3 = csrP[i + 3];
    unsigned u0 = xb[q0.x * 64 + lane];
    unsigned u1 = xb[q1.x * 64 + lane];
    unsigned u2 = xb[q2.x * 64 + lane];
    unsigned u3 = xb[q3.x * 64 + lane];
    float w0 = __int_as_float(q0.y), w1 = __int_as_float(q1.y);
    float w2 = __int_as_float(q2.y), w3 = __int_as_float(q3.y);
    ws += w0 + w1 + w2 + w3;
    float2 f0 = bf2f(u0), f1 = bf2f(u1), f2v = bf2f(u2), f3 = bf2f(u3);
    a0 += w0 * f0.x + w1 * f1.x + w2 * f2v.x + w3 * f3.x;
    a1 += w0 * f0.y + w1 * f1.y + w2 * f2v.y + w3 * f3.y;
  }
  for (; i < end; i++) {
    int2 q = csrP[i];
    unsigned u = xb[q.x * 64 + lane];
    float w = __int_as_float(q.y);
    ws += w;
    float2 f = bf2f(u);
    a0 += w * f.x;
    a1 += w * f.y;
  }
  float inv = 1.f / (1.f + ws);
  return make_float2(a0 * inv, a1 * inv);
}

// ---- GEMM: T in registers (lane L holds dims 2L,2L+1), W bf16 in 32KB LDS,
//      T[k] broadcast via scalar readlane -> only 128 ds_read_b32 per wave ----
#define GEMM2(tv, acc)                                                   \
  {                                                                      \
    _Pragma("unroll") for (int j = 0; j < 2; j++) acc[j] = make_float2(0.f, 0.f); \
    _Pragma("unroll 16") for (int k2 = 0; k2 < 64; k2++) {               \
      float2 w0 = bf2f(Wl[(2 * k2) * 64 + lane]);                        \
      float2 w1 = bf2f(Wl[(2 * k2 + 1) * 64 + lane]);                    \
      _Pragma("unroll") for (int j = 0; j < 2; j++) {                    \
        float bx = rdlane(tv[j].x, k2);                                  \
        float by = rdlane(tv[j].y, k2);                                  \
        acc[j].x += bx * w0.x + by * w1.x;                               \
        acc[j].y += bx * w0.y + by * w1.y;                               \
      }                                                                  \
    }                                                                    \
  }

// F: GCN layer, 8 nodes/block (2 per wave), LDS = 32KB -> 5 blocks/CU.
__global__ __launch_bounds__(256) void kF(const unsigned* __restrict__ xb,
                                          const int* __restrict__ colOffs,
                                          const int2* __restrict__ csrP,
                                          const float* __restrict__ W,
                                          unsigned* __restrict__ outB) {
  __shared__ unsigned Wl[128 * 64];  // bf16x2: Wl[k*64+l] = W[k][2l..2l+1]
  int t = threadIdx.x, lane = t & 63, wv = t >> 6;
  const float4* W4 = (const float4*)W;
  for (int i = t; i < 4096; i += 256) {
    float4 a = W4[i];
    ((uint2*)Wl)[i] = make_uint2(f2bf(a.x, a.y), f2bf(a.z, a.w));
  }
  int nb = blockIdx.x * 8;
  float2 tv[2];
#pragma unroll
  for (int j = 0; j < 2; j++)
    tv[j] = gatherNode(xb, nb + wv * 2 + j, lane, colOffs, csrP);
  __syncthreads();
  float2 acc[2];
  GEMM2(tv, acc)
#pragma unroll
  for (int j = 0; j < 2; j++) {
    int n = nb + wv * 2 + j;
    outB[n * 64 + lane] = f2bf(fmaxf(acc[j].x, 0.f), fmaxf(acc[j].y, 0.f));
  }
}

// H: layer3 + pool + final. Pool accumulation spread over 16 gvec copies
// (contention /16 vs single copy); last block sums copies via memory-side reads.
__global__ __launch_bounds__(256) void kH(const unsigned* __restrict__ xb,
                                          const int* __restrict__ colOffs,
                                          const int2* __restrict__ csrP,
                                          const float* __restrict__ W,
                                          const float* __restrict__ Wc,
                                          float* __restrict__ gvec, unsigned* __restrict__ done,
                                          float* __restrict__ out) {
  __shared__ unsigned Wl[128 * 64];
  int t = threadIdx.x, lane = t & 63, wv = t >> 6;
  const float4* W4 = (const float4*)W;
  for (int i = t; i < 4096; i += 256) {
    float4 a = W4[i];
    ((uint2*)Wl)[i] = make_uint2(f2bf(a.x, a.y), f2bf(a.z, a.w));
  }
  int nb = blockIdx.x * 8;
  float2 tv[2];
#pragma unroll
  for (int j = 0; j < 2; j++)
    tv[j] = gatherNode(xb, nb + wv * 2 + j, lane, colOffs, csrP);
  __syncthreads();
  float2 acc[2];
  GEMM2(tv, acc)
  // pool: H3 never written to memory
  float s0 = fmaxf(acc[0].x, 0.f) + fmaxf(acc[1].x, 0.f);
  float s1 = fmaxf(acc[0].y, 0.f) + fmaxf(acc[1].y, 0.f);
  __syncthreads();  // GEMM done reading Wl; reuse as scratch
  float* gpart = (float*)Wl;
  unsigned* flagp = (unsigned*)Wl + 600;
  if (t < 128) gpart[t] = 0.f;
  __syncthreads();
  atomicAdd(&gpart[2 * lane], s0);
  atomicAdd(&gpart[2 * lane + 1], s1);
  __syncthreads();
  if (t < 128) atomicAdd(&gvec[((blockIdx.x & 15) << 7) + t], gpart[t]);
  asm volatile("s_waitcnt vmcnt(0)" ::: "memory");  // gvec atomics complete (memory-side)
  __syncthreads();
  if (t == 0) *flagp = (atomicAdd(done, 1u) == gridDim.x - 1) ? 1u : 0u;
  __syncthreads();
  if (*flagp) {
    float* f0 = (float*)Wl + 256;
    float* f1 = (float*)Wl + 384;
    if (t < 128) {
      float gj = 0.f;
#pragma unroll
      for (int k = 0; k < 16; k++) gj += atomicAdd(&gvec[k * 128 + t], 0.f);  // memory-side reads
      gj *= (1.0f / 8192.0f);
      f0[t] = gj * Wc[t * 2 + 0];
      f1[t] = gj * Wc[t * 2 + 1];
    }
    __syncthreads();
    for (int o = 64; o > 0; o >>= 1) {
      if (t < o) { f0[t] += f0[t + o]; f1[t] += f1[t + o]; }
      __syncthreads();
    }
    if (t == 0) {
      float l0 = f0[0], l1 = f1[0];
      float m = fmaxf(l0, l1);
      float e0 = __expf(l0 - m), e1 = __expf(l1 - m);
      float inv = 1.f / (e0 + e1);
      out[0] = e0 * inv;
      out[1] = e1 * inv;
    }
  }
}

extern "C" void kernel_launch(void* const* d_in, const int* in_sizes, int n_in,
                              void* d_out, int out_size, void* d_ws, size_t ws_size,
                              hipStream_t stream) {
  const float* x     = (const float*)d_in[0];
  const float* embed = (const float*)d_in[1];
  const float* noise = (const float*)d_in[2];
  const float* tmp   = (const float*)d_in[3];
  const float* gat_W = (const float*)d_in[4];
  const float* att_s = (const float*)d_in[5];
  const float* att_d = (const float*)d_in[6];
  const float* gat_b = (const float*)d_in[7];
  const float* lin_W = (const float*)d_in[8];
  const float* lin_b = (const float*)d_in[9];
  const float* W1    = (const float*)d_in[10];
  const float* W2    = (const float*)d_in[11];
  const float* W3    = (const float*)d_in[12];
  const float* Wc    = (const float*)d_in[13];
  const int* ei      = (const int*)d_in[14];
  const int* nei     = (const int*)d_in[15];
  const int* row = ei;
  const int* col = ei + EE;
  const int* src2 = nei;
  const int* dst2 = nei + E2C;
  float* out = (float*)d_out;

  // workspace layout (4-byte units); 16B/8B-aligned buffers first
  char* w8 = (char*)d_ws;
  size_t off = 0;
  auto alloc = [&](size_t units) -> void* {
    void* p = w8 + off * 4;
    off += units;
    return p;
  };
  float4*   pN      = (float4*)alloc(4 * NN);
  float4*   qN      = (float4*)alloc(4 * NN);
  float2*   asz     = (float2*)alloc(2 * EE);
  int2*     csrP    = (int2*)alloc(2 * EE);
  unsigned* xb      = (unsigned*)alloc(NN * 64);
  unsigned* H1b     = (unsigned*)alloc(NN * 64);
  unsigned* H2b     = (unsigned*)alloc(NN * 64);
  float*    ad      = (float*)alloc(EE);
  int*      colCnt  = (int*)alloc(NN);
  int*      colOffs = (int*)alloc(NN + 2);
  int*      colCur  = (int*)alloc(NN);
  int*      hKeys   = (int*)alloc(HSZ);
  unsigned* hPair   = (unsigned*)alloc(HSZ);
  unsigned* bucket  = (unsigned*)alloc((size_t)NBIN * BCAP);
  unsigned* gCur    = (unsigned*)alloc(NBIN);
  float*    gvec    = (float*)alloc(2048);  // 16 copies x 128
  unsigned* done    = (unsigned*)alloc(2);

  kA<<<512, 256, 0, stream>>>(x, embed, gat_W, att_s, att_d, lin_W, pN, qN, xb,
                              hKeys, hPair, colCnt, gvec, done, gCur);
  kB<<<EE / 256, 256, 0, stream>>>(row, col, pN, qN, asz, ad, colCnt);
  kC<<<321, 256, 0, stream>>>(src2, dst2, colCnt, colOffs, colCur, gCur, bucket);
  kD<<<NBIN, 256, 0, stream>>>(row, col, asz, ad, bucket, gCur, gat_b, lin_W,
                               lin_b, noise, tmp, hKeys, hPair);
  kE<<<EE / 256, 256, 0, stream>>>(row, col, hKeys, hPair, colCur, csrP);
  kF<<<NN / 8, 256, 0, stream>>>(xb, colOffs, csrP, W1, H1b);
  kF<<<NN / 8, 256, 0, stream>>>(H1b, colOffs, csrP, W2, H2b);
  kH<<<NN / 8, 256, 0, stream>>>(H2b, colOffs, csrP, W3, Wc, gvec, done, out);
}

// Round 13
// 227.828 us; speedup vs baseline: 1.7855x; 1.0055x over previous
//
#include <hip/hip_runtime.h>
#include <hip/hip_fp16.h>
#include <math.h>

typedef unsigned long long u64;
typedef __attribute__((ext_vector_type(2))) float fv2;

#define NN 8192
#define EE 81920
#define E2C 1310720
#define HSZ (1 << 18)
#define HMASK (HSZ - 1)
#define NBIN 320     // dst >> 8 : bins of 256 edge-nodes
#define BCAP 4800    // Poisson(4096), +11 sigma
#define SBITS 17     // src index bits in packed u32 payload

__device__ __forceinline__ float wsum(float v) {
#pragma unroll
  for (int m = 32; m > 0; m >>= 1) v += __shfl_xor(v, m, 64);
  return v;
}
__device__ __forceinline__ float lrelu(float x) { return x > 0.f ? x : 0.2f * x; }
__device__ __forceinline__ unsigned packh2(float a, float b) {
  __half2 h = __floats2half2_rn(a, b);
  return *reinterpret_cast<unsigned*>(&h);
}
__device__ __forceinline__ void atomic_pk_add_f16(unsigned* addr, unsigned data) {
  asm volatile("global_atomic_pk_add_f16 %0, %1, off" :: "v"(addr), "v"(data) : "memory");
}
__device__ __forceinline__ int hfind(const int* __restrict__ keys, int key) {
  unsigned i = ((unsigned)key * 2654435761u) >> 14 & HMASK;
  while (true) {
    int k = keys[i];
    if (k == key) return (int)i;
    if (k == -1) return -1;
    i = (i + 1) & HMASK;
  }
}
// bf16 helpers
__device__ __forceinline__ float2 bf2f(unsigned u) {
  return make_float2(__uint_as_float(u << 16), __uint_as_float(u & 0xffff0000u));
}
__device__ __forceinline__ unsigned f2bf(float a, float b) {
  unsigned ua = __float_as_uint(a);
  ua = (ua + 0x7fffu + ((ua >> 16) & 1u)) >> 16;
  unsigned ub = __float_as_uint(b);
  ub = ((ub + 0x7fffu + ((ub >> 16) & 1u)) >> 16) << 16;
  return (ua & 0xffffu) | ub;
}
__device__ __forceinline__ unsigned f2bf1(float a) {
  unsigned ua = __float_as_uint(a);
  return (ua + 0x7fffu + ((ua >> 16) & 1u)) >> 16;
}
__device__ __forceinline__ float bf1f(unsigned u) { return __uint_as_float(u << 16); }
// fp8 e4m3 pack/unpack (HW cvt, gfx950 OCP)
__device__ __forceinline__ unsigned short f2fp8x2(float a, float b) {
  return (unsigned short)(__builtin_amdgcn_cvt_pk_fp8_f32(a, b, 0, false) & 0xffff);
}
__device__ __forceinline__ float2 fp8x2f(unsigned short v) {
  fv2 f = __builtin_amdgcn_cvt_pk_f32_fp8((int)(unsigned)v, false);
  return make_float2(f[0], f[1]);
}
// wave-uniform broadcast of lane k's value via scalar readlane (no LDS traffic)
__device__ __forceinline__ float rdlane(float v, int k) {
  return __uint_as_float(__builtin_amdgcn_readlane(__float_as_uint(v), k));
}

// A: init + x->fp8 + per-block combo in LDS + node scalars. 512 blocks.
__global__ __launch_bounds__(256) void kA(const float* __restrict__ x,
                                          const float* __restrict__ embed,
                                          const float* __restrict__ gw,
                                          const float* __restrict__ att_s,
                                          const float* __restrict__ att_d,
                                          const float* __restrict__ lin_W,
                                          float4* __restrict__ pN, float4* __restrict__ qN,
                                          unsigned short* __restrict__ xbu,
                                          int* __restrict__ hKeys, unsigned* __restrict__ hPair,
                                          int* __restrict__ colCnt, float* __restrict__ gvec,
                                          unsigned* __restrict__ done, unsigned* __restrict__ gCur) {
  __shared__ float sm[768];  // cA | cD | cZ
  int t = threadIdx.x, bid = blockIdx.x;
  int lane = t & 63, wv = t >> 6;
  for (int i = bid * 256 + t; i < HSZ; i += 512 * 256) { hKeys[i] = -1; hPair[i] = 0u; }
  for (int i = bid * 256 + t; i < NN; i += 512 * 256) colCnt[i] = 0;
  if (bid == 0) {
    for (int i = t; i < 2048; i += 256) gvec[i] = 0.f;  // 16 contention-spread copies
    if (t == 0) *done = 0u;
    for (int i = t; i < NBIN; i += 256) gCur[i] = 0u;
  }
  {  // x -> fp8 e4m3: thread handles node bid*16+(t>>4), dims (t&15)*8 .. +7
    int n = bid * 16 + (t >> 4);
    int dp = (t & 15) * 8;
    const float4* x4 = (const float4*)(x + n * 128 + dp);
    float4 a = x4[0], b = x4[1];
    unsigned p0 = f2fp8x2(a.x, a.y), p1 = f2fp8x2(a.z, a.w);
    unsigned p2 = f2fp8x2(b.x, b.y), p3 = f2fp8x2(b.z, b.w);
    ((uint2*)xbu)[n * 16 + (t & 15)] = make_uint2(p0 | (p1 << 16), p2 | (p3 << 16));
  }
  {
    float sa = 0.f, sd = 0.f, sz = 0.f;
#pragma unroll 8
    for (int k = 0; k < 64; k++) {
      float w = gw[t * 64 + k];
      sa += w * att_s[k]; sd += w * att_d[k]; sz += w * lin_W[k];
    }
    sm[t] = sa; sm[256 + t] = sd; sm[512 + t] = sz;
  }
  __syncthreads();
#pragma unroll
  for (int j = 0; j < 4; j++) {
    int n = bid * 16 + wv * 4 + j;
    float e0 = embed[n * 128 + lane], e1 = embed[n * 128 + 64 + lane];
    float pA = wsum(e0 * sm[lane] + e1 * sm[64 + lane]);
    float qA = wsum(e0 * sm[128 + lane] + e1 * sm[192 + lane]);
    float pD = wsum(e0 * sm[256 + lane] + e1 * sm[320 + lane]);
    float qD = wsum(e0 * sm[384 + lane] + e1 * sm[448 + lane]);
    float pZ = wsum(e0 * sm[512 + lane] + e1 * sm[576 + lane]);
    float qZ = wsum(e0 * sm[640 + lane] + e1 * sm[704 + lane]);
    if (lane == 0) pN[n] = make_float4(pA, pD, pZ, 0.f);
    if (lane == 1) qN[n] = make_float4(qA, qD, qZ, 0.f);
  }
}

// B: per-edge scalars + col histogram
__global__ void kB(const int* __restrict__ row, const int* __restrict__ col,
                   const float4* __restrict__ pN, const float4* __restrict__ qN,
                   float2* __restrict__ asz, float* __restrict__ ad, int* __restrict__ colCnt) {
  int e = blockIdx.x * 256 + threadIdx.x;
  int r = row[e], c = col[e];
  float4 p = pN[r];
  float4 q = qN[c];
  asz[e] = make_float2(p.x + q.x, p.z + q.z);  // {a_s, z}
  ad[e] = p.y + q.y;
  atomicAdd(&colCnt[c], 1);
}

// C: blocks 0..319 partition edge2 into 320 dst bins; block 320 scans colCnt.
__global__ __launch_bounds__(256) void kC(const int* __restrict__ src2, const int* __restrict__ dst2,
                                          const int* __restrict__ colCnt, int* __restrict__ colOffs,
                                          int* __restrict__ colCur,
                                          unsigned* __restrict__ gCur, unsigned* __restrict__ bucket) {
  int t = threadIdx.x;
  if (blockIdx.x == 320) {
    __shared__ int sd32[256];
    int beg = t * 32;
    int s = 0;
#pragma unroll 8
    for (int i = 0; i < 32; i++) s += colCnt[beg + i];
    sd32[t] = s;
    __syncthreads();
    for (int o = 1; o < 256; o <<= 1) {
      int v = (t >= o) ? sd32[t - o] : 0;
      __syncthreads();
      sd32[t] += v;
      __syncthreads();
    }
    int run = (t == 0) ? 0 : sd32[t - 1];
    for (int i = 0; i < 32; i++) {
      colOffs[beg + i] = run;
      colCur[beg + i] = run;
      run += colCnt[beg + i];
    }
    if (t == 255) colOffs[NN] = run;
    return;
  }
  __shared__ unsigned hist[NBIN], base[NBIN], lcur[NBIN];
  for (int i = t; i < NBIN; i += 256) { hist[i] = 0u; lcur[i] = 0u; }
  __syncthreads();
  int blockBase = blockIdx.x * 4096;
  int4 dv[4];
#pragma unroll
  for (int j = 0; j < 4; j++) {
    dv[j] = *(const int4*)&dst2[blockBase + j * 1024 + t * 4];
    atomicAdd(&hist[dv[j].x >> 8], 1u);
    atomicAdd(&hist[dv[j].y >> 8], 1u);
    atomicAdd(&hist[dv[j].z >> 8], 1u);
    atomicAdd(&hist[dv[j].w >> 8], 1u);
  }
  __syncthreads();
  for (int i = t; i < NBIN; i += 256)
    if (hist[i]) base[i] = atomicAdd(&gCur[i], hist[i]);
  __syncthreads();
#pragma unroll
  for (int j = 0; j < 4; j++) {
    int4 sv = *(const int4*)&src2[blockBase + j * 1024 + t * 4];
    int ss[4] = {sv.x, sv.y, sv.z, sv.w};
    int dd[4] = {dv[j].x, dv[j].y, dv[j].z, dv[j].w};
#pragma unroll
    for (int k = 0; k < 4; k++) {
      int s = ss[k], d = dd[k];
      int b = d >> 8;
      unsigned r = atomicAdd(&lcur[b], 1u);
      unsigned pos = base[b] + r;
      if (pos < BCAP) bucket[(size_t)b * BCAP + pos] = ((unsigned)(d & 255) << SBITS) | (unsigned)s;
    }
  }
}

// D: per-bin reduce (4-wide ILP) + gate + hash insert
__global__ __launch_bounds__(256) void kD(const int* __restrict__ row, const int* __restrict__ col,
                                          const float2* __restrict__ asz, const float* __restrict__ ad,
                                          const unsigned* __restrict__ bucket, const unsigned* __restrict__ gCur,
                                          const float* __restrict__ gat_b, const float* __restrict__ lin_W,
                                          const float* __restrict__ lin_b, const float* __restrict__ noise,
                                          const float* __restrict__ tmp,
                                          int* __restrict__ hKeys, unsigned* __restrict__ hPair) {
  __shared__ float acc[512];
  __shared__ float adl[256];
  int b = blockIdx.x, t = threadIdx.x, lane = t & 63;
  acc[2 * t] = 0.f; acc[2 * t + 1] = 0.f; adl[t] = ad[b * 256 + t];
  __syncthreads();
  int cnt = min((int)gCur[b], BCAP);
  const unsigned* bp = bucket + (size_t)b * BCAP;
  const unsigned SM = (1u << SBITS) - 1;
  int i = t;
  for (; i + 768 < cnt; i += 1024) {
    unsigned u0 = bp[i], u1 = bp[i + 256], u2 = bp[i + 512], u3 = bp[i + 768];
    float2 az0 = asz[u0 & SM], az1 = asz[u1 & SM], az2 = asz[u2 & SM], az3 = asz[u3 & SM];
    int l0 = u0 >> SBITS, l1 = u1 >> SBITS, l2 = u2 >> SBITS, l3 = u3 >> SBITS;
    float ea0 = __expf(lrelu(az0.x + adl[l0]));
    float ea1 = __expf(lrelu(az1.x + adl[l1]));
    float ea2 = __expf(lrelu(az2.x + adl[l2]));
    float ea3 = __expf(lrelu(az3.x + adl[l3]));
    atomicAdd(&acc[2 * l0], ea0); atomicAdd(&acc[2 * l0 + 1], ea0 * az0.y);
    atomicAdd(&acc[2 * l1], ea1); atomicAdd(&acc[2 * l1 + 1], ea1 * az1.y);
    atomicAdd(&acc[2 * l2], ea2); atomicAdd(&acc[2 * l2 + 1], ea2 * az2.y);
    atomicAdd(&acc[2 * l3], ea3); atomicAdd(&acc[2 * l3 + 1], ea3 * az3.y);
  }
  for (; i < cnt; i += 256) {
    unsigned u = bp[i];
    float2 az = asz[u & SM];
    int l = u >> SBITS;
    float ea = __expf(lrelu(az.x + adl[l]));
    atomicAdd(&acc[2 * l], ea);
    atomicAdd(&acc[2 * l + 1], ea * az.y);
  }
  __syncthreads();
  float gb = wsum(gat_b[lane] * lin_W[lane]) + lin_b[0];
  float itmp = 1.f / tmp[0];
  {
    int e = b * 256 + t;
    float2 szv = asz[e];
    float eself = __expf(lrelu(szv.x + adl[t]));
    float la = (acc[2 * t + 1] + eself * szv.y) / (acc[2 * t] + eself) + gb;
    float ns = noise[e];
    float g = (logf(ns) - log1pf(-ns) + la) * itmp;
    float gate = 1.f / (1.f + __expf(-g));
    int key = row[e] * NN + col[e];
    unsigned hi = ((unsigned)key * 2654435761u) >> 14 & HMASK;
    while (true) {
      int old = atomicCAS(&hKeys[hi], -1, key);
      if (old == -1 || old == key) break;
      hi = (hi + 1) & HMASK;
    }
    atomic_pk_add_f16(&hPair[hi], packh2(1.0f, gate));
  }
}

// E: edge_mask -> w; CSR scatter packed u32: (w_bf16 << 16) | row(13b)
__global__ void kE(const int* __restrict__ row, const int* __restrict__ col,
                   const int* __restrict__ hKeys, const unsigned* __restrict__ hPair,
                   int* __restrict__ colCur, unsigned* __restrict__ csrW) {
  int e = blockIdx.x * 256 + threadIdx.x;
  int r = row[e], c = col[e];
  int s1 = hfind(hKeys, r * NN + c);
  unsigned u1 = hPair[s1];
  __half2 h1 = *reinterpret_cast<__half2*>(&u1);
  float cv = __low2float(h1), g1 = __high2float(h1);
  int s2 = hfind(hKeys, c * NN + r);
  float g2 = 0.f;
  if (s2 >= 0) {
    unsigned u2 = hPair[s2];
    g2 = __high2float(*reinterpret_cast<__half2*>(&u2));
  }
  float em = cv * 0.5f * (g1 + g2);
  float w = 1.f / (1.f + __expf(-em));
  int pos = atomicAdd(&colCur[c], 1);
  csrW[pos] = (f2bf1(w) << 16) | (unsigned)r;
}

// gather one node's aggregated features (fp8 rows = 128B, 4-wide ILP); returns f32 pair
__device__ __forceinline__ float2 gatherNode(const unsigned short* __restrict__ xb, int n, int lane,
                                             const int* __restrict__ colOffs,
                                             const unsigned* __restrict__ csrW) {
  float2 sf = fp8x2f(xb[n * 64 + lane]);
  float a0 = sf.x, a1 = sf.y, ws = 0.f;
  int off = colOffs[n], end = colOffs[n + 1];
  int i = off;
  for (; i + 4 <= end; i += 4) {
    unsigned q0 = csrW[i], q1 = csrW[i + 1], q2 = csrW[i + 2], q3 = csrW[i + 3];
    unsigned short u0 = xb[(q0 & 0x1fff) * 64 + lane];
    unsigned short u1 = xb[(q1 & 0x1fff) * 64 + lane];
    unsigned short u2 = xb[(q2 & 0x1fff) * 64 + lane];
    unsigned short u3 = xb[(q3 & 0x1fff) * 64 + lane];
    float w0 = bf1f(q0 >> 16), w1 = bf1f(q1 >> 16);
    float w2 = bf1f(q2 >> 16), w3 = bf1f(q3 >> 16);
    ws += w0 + w1 + w2 + w3;
    float2 f0 = fp8x2f(u0), f1 = fp8x2f(u1), f2v = fp8x2f(u2), f3 = fp8x2f(u3);
    a0 += w0 * f0.x + w1 * f1.x + w2 * f2v.x + w3 * f3.x;
    a1 += w0 * f0.y + w1 * f1.y + w2 * f2v.y + w3 * f3.y;
  }
  for (; i < end; i++) {
    unsigned q = csrW[i];
    unsigned short u = xb[(q & 0x1fff) * 64 + lane];
    float w = bf1f(q >> 16);
    ws += w;
    float2 f = fp8x2f(u);
    a0 += w * f.x;
    a1 += w * f.y;
  }
  float inv = 1.f / (1.f + ws);
  return make_float2(a0 * inv, a1 * inv);
}

// ---- GEMM: T in registers (lane L holds dims 2L,2L+1), W bf16 in 32KB LDS,
//      T[k] broadcast via scalar readlane ----
#define GEMM2(tv, acc)                                                   \
  {                                                                      \
    _Pragma("unroll") for (int j = 0; j < 2; j++) acc[j] = make_float2(0.f, 0.f); \
    _Pragma("unroll 16") for (int k2 = 0; k2 < 64; k2++) {               \
      float2 w0 = bf2f(Wl[(2 * k2) * 64 + lane]);                        \
      float2 w1 = bf2f(Wl[(2 * k2 + 1) * 64 + lane]);                    \
      _Pragma("unroll") for (int j = 0; j < 2; j++) {                    \
        float bx = rdlane(tv[j].x, k2);                                  \
        float by = rdlane(tv[j].y, k2);                                  \
        acc[j].x += bx * w0.x + by * w1.x;                               \
        acc[j].y += bx * w0.y + by * w1.y;                               \
      }                                                                  \
    }                                                                    \
  }

// F: GCN layer, 8 nodes/block (2 per wave), LDS = 32KB.
__global__ __launch_bounds__(256) void kF(const unsigned short* __restrict__ xb,
                                          const int* __restrict__ colOffs,
                                          const unsigned* __restrict__ csrW,
                                          const float* __restrict__ W,
                                          unsigned short* __restrict__ outB) {
  __shared__ unsigned Wl[128 * 64];  // bf16x2: Wl[k*64+l] = W[k][2l..2l+1]
  int t = threadIdx.x, lane = t & 63, wv = t >> 6;
  const float4* W4 = (const float4*)W;
  for (int i = t; i < 4096; i += 256) {
    float4 a = W4[i];
    ((uint2*)Wl)[i] = make_uint2(f2bf(a.x, a.y), f2bf(a.z, a.w));
  }
  int nb = blockIdx.x * 8;
  float2 tv[2];
#pragma unroll
  for (int j = 0; j < 2; j++)
    tv[j] = gatherNode(xb, nb + wv * 2 + j, lane, colOffs, csrW);
  __syncthreads();
  float2 acc[2];
  GEMM2(tv, acc)
#pragma unroll
  for (int j = 0; j < 2; j++) {
    int n = nb + wv * 2 + j;
    outB[n * 64 + lane] = f2fp8x2(fmaxf(acc[j].x, 0.f), fmaxf(acc[j].y, 0.f));
  }
}

// H: layer3 + pool + final. Pool accumulation spread over 16 gvec copies.
__global__ __launch_bounds__(256) void kH(const unsigned short* __restrict__ xb,
                                          const int* __restrict__ colOffs,
                                          const unsigned* __restrict__ csrW,
                                          const float* __restrict__ W,
                                          const float* __restrict__ Wc,
                                          float* __restrict__ gvec, unsigned* __restrict__ done,
                                          float* __restrict__ out) {
  __shared__ unsigned Wl[128 * 64];
  int t = threadIdx.x, lane = t & 63, wv = t >> 6;
  const float4* W4 = (const float4*)W;
  for (int i = t; i < 4096; i += 256) {
    float4 a = W4[i];
    ((uint2*)Wl)[i] = make_uint2(f2bf(a.x, a.y), f2bf(a.z, a.w));
  }
  int nb = blockIdx.x * 8;
  float2 tv[2];
#pragma unroll
  for (int j = 0; j < 2; j++)
    tv[j] = gatherNode(xb, nb + wv * 2 + j, lane, colOffs, csrW);
  __syncthreads();
  float2 acc[2];
  GEMM2(tv, acc)
  // pool: H3 never written to memory
  float s0 = fmaxf(acc[0].x, 0.f) + fmaxf(acc[1].x, 0.f);
  float s1 = fmaxf(acc[0].y, 0.f) + fmaxf(acc[1].y, 0.f);
  __syncthreads();  // GEMM done reading Wl; reuse as scratch
  float* gpart = (float*)Wl;
  unsigned* flagp = (unsigned*)Wl + 600;
  if (t < 128) gpart[t] = 0.f;
  __syncthreads();
  atomicAdd(&gpart[2 * lane], s0);
  atomicAdd(&gpart[2 * lane + 1], s1);
  __syncthreads();
  if (t < 128) atomicAdd(&gvec[((blockIdx.x & 15) << 7) + t], gpart[t]);
  asm volatile("s_waitcnt vmcnt(0)" ::: "memory");  // gvec atomics complete (memory-side)
  __syncthreads();
  if (t == 0) *flagp = (atomicAdd(done, 1u) == gridDim.x - 1) ? 1u : 0u;
  __syncthreads();
  if (*flagp) {
    float* f0 = (float*)Wl + 256;
    float* f1 = (float*)Wl + 384;
    if (t < 128) {
      float gj = 0.f;
#pragma unroll
      for (int k = 0; k < 16; k++) gj += atomicAdd(&gvec[k * 128 + t], 0.f);  // memory-side reads
      gj *= (1.0f / 8192.0f);
      f0[t] = gj * Wc[t * 2 + 0];
      f1[t] = gj * Wc[t * 2 + 1];
    }
    __syncthreads();
    for (int o = 64; o > 0; o >>= 1) {
      if (t < o) { f0[t] += f0[t + o]; f1[t] += f1[t + o]; }
      __syncthreads();
    }
    if (t == 0) {
      float l0 = f0[0], l1 = f1[0];
      float m = fmaxf(l0, l1);
      float e0 = __expf(l0 - m), e1 = __expf(l1 - m);
      float inv = 1.f / (e0 + e1);
      out[0] = e0 * inv;
      out[1] = e1 * inv;
    }
  }
}

extern "C" void kernel_launch(void* const* d_in, const int* in_sizes, int n_in,
                              void* d_out, int out_size, void* d_ws, size_t ws_size,
                              hipStream_t stream) {
  const float* x     = (const float*)d_in[0];
  const float* embed = (const float*)d_in[1];
  const float* noise = (const float*)d_in[2];
  const float* tmp   = (const float*)d_in[3];
  const float* gat_W = (const float*)d_in[4];
  const float* att_s = (const float*)d_in[5];
  const float* att_d = (const float*)d_in[6];
  const float* gat_b = (const float*)d_in[7];
  const float* lin_W = (const float*)d_in[8];
  const float* lin_b = (const float*)d_in[9];
  const float* W1    = (const float*)d_in[10];
  const float* W2    = (const float*)d_in[11];
  const float* W3    = (const float*)d_in[12];
  const float* Wc    = (const float*)d_in[13];
  const int* ei      = (const int*)d_in[14];
  const int* nei     = (const int*)d_in[15];
  const int* row = ei;
  const int* col = ei + EE;
  const int* src2 = nei;
  const int* dst2 = nei + E2C;
  float* out = (float*)d_out;

  // workspace layout (4-byte units); 16B/8B-aligned buffers first
  char* w8 = (char*)d_ws;
  size_t off = 0;
  auto alloc = [&](size_t units) -> void* {
    void* p = w8 + off * 4;
    off += units;
    return p;
  };
  float4*   pN      = (float4*)alloc(4 * NN);
  float4*   qN      = (float4*)alloc(4 * NN);
  float2*   asz     = (float2*)alloc(2 * EE);
  unsigned short* xbu = (unsigned short*)alloc(NN * 32);  // fp8x2 per lane
  unsigned short* H1u = (unsigned short*)alloc(NN * 32);
  unsigned short* H2u = (unsigned short*)alloc(NN * 32);
  unsigned* csrW    = (unsigned*)alloc(EE);
  float*    ad      = (float*)alloc(EE);
  int*      colCnt  = (int*)alloc(NN);
  int*      colOffs = (int*)alloc(NN + 2);
  int*      colCur  = (int*)alloc(NN);
  int*      hKeys   = (int*)alloc(HSZ);
  unsigned* hPair   = (unsigned*)alloc(HSZ);
  unsigned* bucket  = (unsigned*)alloc((size_t)NBIN * BCAP);
  unsigned* gCur    = (unsigned*)alloc(NBIN);
  float*    gvec    = (float*)alloc(2048);  // 16 copies x 128
  unsigned* done    = (unsigned*)alloc(2);

  kA<<<512, 256, 0, stream>>>(x, embed, gat_W, att_s, att_d, lin_W, pN, qN, xbu,
                              hKeys, hPair, colCnt, gvec, done, gCur);
  kB<<<EE / 256, 256, 0, stream>>>(row, col, pN, qN, asz, ad, colCnt);
  kC<<<321, 256, 0, stream>>>(src2, dst2, colCnt, colOffs, colCur, gCur, bucket);
  kD<<<NBIN, 256, 0, stream>>>(row, col, asz, ad, bucket, gCur, gat_b, lin_W,
                               lin_b, noise, tmp, hKeys, hPair);
  kE<<<EE / 256, 256, 0, stream>>>(row, col, hKeys, hPair, colCur, csrW);
  kF<<<NN / 8, 256, 0, stream>>>(xbu, colOffs, csrW, W1, H1u);
  kF<<<NN / 8, 256, 0, stream>>>(H1u, colOffs, csrW, W2, H2u);
  kH<<<NN / 8, 256, 0, stream>>>(H2u, colOffs, csrW, W3, Wc, gvec, done, out);
}

// Round 14
// 226.313 us; speedup vs baseline: 1.7974x; 1.0067x over previous
//
#include <hip/hip_runtime.h>
#include <hip/hip_fp16.h>
#include <math.h>

typedef unsigned long long u64;
typedef __attribute__((ext_vector_type(2))) float fv2;

#define NN 8192
#define EE 81920
#define E2C 1310720
#define HSZ (1 << 18)
#define HMASK (HSZ - 1)
#define NBIN 320     // dst >> 8 : bins of 256 edge-nodes
#define BCAP 4800    // Poisson(4096), +11 sigma
#define SBITS 17     // src index bits in packed u32 payload

__device__ __forceinline__ float wsum(float v) {
#pragma unroll
  for (int m = 32; m > 0; m >>= 1) v += __shfl_xor(v, m, 64);
  return v;
}
__device__ __forceinline__ float lrelu(float x) { return x > 0.f ? x : 0.2f * x; }
__device__ __forceinline__ unsigned packh2(float a, float b) {
  __half2 h = __floats2half2_rn(a, b);
  return *reinterpret_cast<unsigned*>(&h);
}
__device__ __forceinline__ void atomic_pk_add_f16(unsigned* addr, unsigned data) {
  asm volatile("global_atomic_pk_add_f16 %0, %1, off" :: "v"(addr), "v"(data) : "memory");
}
__device__ __forceinline__ int hfind(const int* __restrict__ keys, int key) {
  unsigned i = ((unsigned)key * 2654435761u) >> 14 & HMASK;
  while (true) {
    int k = keys[i];
    if (k == key) return (int)i;
    if (k == -1) return -1;
    i = (i + 1) & HMASK;
  }
}
// bf16 helpers
__device__ __forceinline__ float2 bf2f(unsigned u) {
  return make_float2(__uint_as_float(u << 16), __uint_as_float(u & 0xffff0000u));
}
__device__ __forceinline__ unsigned f2bf(float a, float b) {
  unsigned ua = __float_as_uint(a);
  ua = (ua + 0x7fffu + ((ua >> 16) & 1u)) >> 16;
  unsigned ub = __float_as_uint(b);
  ub = ((ub + 0x7fffu + ((ub >> 16) & 1u)) >> 16) << 16;
  return (ua & 0xffffu) | ub;
}
__device__ __forceinline__ unsigned f2bf1(float a) {
  unsigned ua = __float_as_uint(a);
  return (ua + 0x7fffu + ((ua >> 16) & 1u)) >> 16;
}
__device__ __forceinline__ float bf1f(unsigned u) { return __uint_as_float(u << 16); }
// fp8 e4m3 pack/unpack (HW cvt, gfx950 OCP)
__device__ __forceinline__ unsigned short f2fp8x2(float a, float b) {
  return (unsigned short)(__builtin_amdgcn_cvt_pk_fp8_f32(a, b, 0, false) & 0xffff);
}
__device__ __forceinline__ float2 fp8x2f(unsigned short v) {
  fv2 f = __builtin_amdgcn_cvt_pk_f32_fp8((int)(unsigned)v, false);
  return make_float2(f[0], f[1]);
}
// wave-uniform broadcast of lane k's value via scalar readlane (no LDS traffic)
__device__ __forceinline__ float rdlane(float v, int k) {
  return __uint_as_float(__builtin_amdgcn_readlane(__float_as_uint(v), k));
}

// A: init + x->fp8 + per-block combo in LDS + node scalars. 512 blocks.
__global__ __launch_bounds__(256) void kA(const float* __restrict__ x,
                                          const float* __restrict__ embed,
                                          const float* __restrict__ gw,
                                          const float* __restrict__ att_s,
                                          const float* __restrict__ att_d,
                                          const float* __restrict__ lin_W,
                                          float4* __restrict__ pN, float4* __restrict__ qN,
                                          unsigned short* __restrict__ xbu,
                                          int* __restrict__ hKeys, unsigned* __restrict__ hPair,
                                          int* __restrict__ colCnt, float* __restrict__ gvec,
                                          unsigned* __restrict__ done, unsigned* __restrict__ gCur) {
  __shared__ float sm[768];  // cA | cD | cZ
  int t = threadIdx.x, bid = blockIdx.x;
  int lane = t & 63, wv = t >> 6;
  for (int i = bid * 256 + t; i < HSZ; i += 512 * 256) { hKeys[i] = -1; hPair[i] = 0u; }
  for (int i = bid * 256 + t; i < NN; i += 512 * 256) colCnt[i] = 0;
  if (bid == 0) {
    for (int i = t; i < 2048; i += 256) gvec[i] = 0.f;  // 16 contention-spread copies
    if (t == 0) *done = 0u;
    for (int i = t; i < NBIN; i += 256) gCur[i] = 0u;
  }
  {  // x -> fp8 e4m3: thread handles node bid*16+(t>>4), dims (t&15)*8 .. +7
    int n = bid * 16 + (t >> 4);
    int dp = (t & 15) * 8;
    const float4* x4 = (const float4*)(x + n * 128 + dp);
    float4 a = x4[0], b = x4[1];
    unsigned p0 = f2fp8x2(a.x, a.y), p1 = f2fp8x2(a.z, a.w);
    unsigned p2 = f2fp8x2(b.x, b.y), p3 = f2fp8x2(b.z, b.w);
    ((uint2*)xbu)[n * 16 + (t & 15)] = make_uint2(p0 | (p1 << 16), p2 | (p3 << 16));
  }
  {
    float sa = 0.f, sd = 0.f, sz = 0.f;
#pragma unroll 8
    for (int k = 0; k < 64; k++) {
      float w = gw[t * 64 + k];
      sa += w * att_s[k]; sd += w * att_d[k]; sz += w * lin_W[k];
    }
    sm[t] = sa; sm[256 + t] = sd; sm[512 + t] = sz;
  }
  __syncthreads();
#pragma unroll
  for (int j = 0; j < 4; j++) {
    int n = bid * 16 + wv * 4 + j;
    float e0 = embed[n * 128 + lane], e1 = embed[n * 128 + 64 + lane];
    float pA = wsum(e0 * sm[lane] + e1 * sm[64 + lane]);
    float qA = wsum(e0 * sm[128 + lane] + e1 * sm[192 + lane]);
    float pD = wsum(e0 * sm[256 + lane] + e1 * sm[320 + lane]);
    float qD = wsum(e0 * sm[384 + lane] + e1 * sm[448 + lane]);
    float pZ = wsum(e0 * sm[512 + lane] + e1 * sm[576 + lane]);
    float qZ = wsum(e0 * sm[640 + lane] + e1 * sm[704 + lane]);
    if (lane == 0) pN[n] = make_float4(pA, pD, pZ, 0.f);
    if (lane == 1) qN[n] = make_float4(qA, qD, qZ, 0.f);
  }
}

// C: 320 blocks. Each block: (1) per-edge scalars for its 256 edges (ex-kB, hides
// in the cold src2/dst2 read latency), (2) partition its 4096 edge2 entries into bins.
// colCnt scan moved to kD (colCnt complete only at this kernel's end).
__global__ __launch_bounds__(256) void kC(const int* __restrict__ row, const int* __restrict__ col,
                                          const float4* __restrict__ pN, const float4* __restrict__ qN,
                                          float2* __restrict__ asz, float* __restrict__ ad,
                                          int* __restrict__ colCnt,
                                          const int* __restrict__ src2, const int* __restrict__ dst2,
                                          unsigned* __restrict__ gCur, unsigned* __restrict__ bucket) {
  __shared__ unsigned hist[NBIN], base[NBIN], lcur[NBIN];
  int t = threadIdx.x;
  for (int i = t; i < NBIN; i += 256) { hist[i] = 0u; lcur[i] = 0u; }
  int blockBase = blockIdx.x * 4096;
  // ex-kB: per-edge scalars + col histogram for edge e
  {
    int e = blockIdx.x * 256 + t;
    int r = row[e], c = col[e];
    float4 p = pN[r];
    float4 q = qN[c];
    asz[e] = make_float2(p.x + q.x, p.z + q.z);  // {a_s, z}
    ad[e] = p.y + q.y;
    atomicAdd(&colCnt[c], 1);
  }
  __syncthreads();
  int4 dv[4];
#pragma unroll
  for (int j = 0; j < 4; j++) {
    dv[j] = *(const int4*)&dst2[blockBase + j * 1024 + t * 4];
    atomicAdd(&hist[dv[j].x >> 8], 1u);
    atomicAdd(&hist[dv[j].y >> 8], 1u);
    atomicAdd(&hist[dv[j].z >> 8], 1u);
    atomicAdd(&hist[dv[j].w >> 8], 1u);
  }
  __syncthreads();
  for (int i = t; i < NBIN; i += 256)
    if (hist[i]) base[i] = atomicAdd(&gCur[i], hist[i]);
  __syncthreads();
#pragma unroll
  for (int j = 0; j < 4; j++) {
    int4 sv = *(const int4*)&src2[blockBase + j * 1024 + t * 4];
    int ss[4] = {sv.x, sv.y, sv.z, sv.w};
    int dd[4] = {dv[j].x, dv[j].y, dv[j].z, dv[j].w};
#pragma unroll
    for (int k = 0; k < 4; k++) {
      int s = ss[k], d = dd[k];
      int b = d >> 8;
      unsigned r = atomicAdd(&lcur[b], 1u);
      unsigned pos = base[b] + r;
      if (pos < BCAP) bucket[(size_t)b * BCAP + pos] = ((unsigned)(d & 255) << SBITS) | (unsigned)s;
    }
  }
}

// D: blocks 0..319: per-bin reduce (4-wide ILP) + gate + hash insert.
//    block 320: exclusive scan of colCnt -> colOffs/colCur (needed by kE only).
__global__ __launch_bounds__(256) void kD(const int* __restrict__ row, const int* __restrict__ col,
                                          const float2* __restrict__ asz, const float* __restrict__ ad,
                                          const unsigned* __restrict__ bucket, const unsigned* __restrict__ gCur,
                                          const float* __restrict__ gat_b, const float* __restrict__ lin_W,
                                          const float* __restrict__ lin_b, const float* __restrict__ noise,
                                          const float* __restrict__ tmp,
                                          int* __restrict__ hKeys, unsigned* __restrict__ hPair,
                                          const int* __restrict__ colCnt, int* __restrict__ colOffs,
                                          int* __restrict__ colCur) {
  __shared__ float acc[512];
  __shared__ float adl[256];
  int b = blockIdx.x, t = threadIdx.x, lane = t & 63;
  if (b == NBIN) {  // scan block
    __shared__ int sd32[256];
    int beg = t * 32;
    int s = 0;
#pragma unroll 8
    for (int i = 0; i < 32; i++) s += colCnt[beg + i];
    sd32[t] = s;
    __syncthreads();
    for (int o = 1; o < 256; o <<= 1) {
      int v = (t >= o) ? sd32[t - o] : 0;
      __syncthreads();
      sd32[t] += v;
      __syncthreads();
    }
    int run = (t == 0) ? 0 : sd32[t - 1];
    for (int i = 0; i < 32; i++) {
      colOffs[beg + i] = run;
      colCur[beg + i] = run;
      run += colCnt[beg + i];
    }
    if (t == 255) colOffs[NN] = run;
    return;
  }
  acc[2 * t] = 0.f; acc[2 * t + 1] = 0.f; adl[t] = ad[b * 256 + t];
  __syncthreads();
  int cnt = min((int)gCur[b], BCAP);
  const unsigned* bp = bucket + (size_t)b * BCAP;
  const unsigned SM = (1u << SBITS) - 1;
  int i = t;
  for (; i + 768 < cnt; i += 1024) {
    unsigned u0 = bp[i], u1 = bp[i + 256], u2 = bp[i + 512], u3 = bp[i + 768];
    float2 az0 = asz[u0 & SM], az1 = asz[u1 & SM], az2 = asz[u2 & SM], az3 = asz[u3 & SM];
    int l0 = u0 >> SBITS, l1 = u1 >> SBITS, l2 = u2 >> SBITS, l3 = u3 >> SBITS;
    float ea0 = __expf(lrelu(az0.x + adl[l0]));
    float ea1 = __expf(lrelu(az1.x + adl[l1]));
    float ea2 = __expf(lrelu(az2.x + adl[l2]));
    float ea3 = __expf(lrelu(az3.x + adl[l3]));
    atomicAdd(&acc[2 * l0], ea0); atomicAdd(&acc[2 * l0 + 1], ea0 * az0.y);
    atomicAdd(&acc[2 * l1], ea1); atomicAdd(&acc[2 * l1 + 1], ea1 * az1.y);
    atomicAdd(&acc[2 * l2], ea2); atomicAdd(&acc[2 * l2 + 1], ea2 * az2.y);
    atomicAdd(&acc[2 * l3], ea3); atomicAdd(&acc[2 * l3 + 1], ea3 * az3.y);
  }
  for (; i < cnt; i += 256) {
    unsigned u = bp[i];
    float2 az = asz[u & SM];
    int l = u >> SBITS;
    float ea = __expf(lrelu(az.x + adl[l]));
    atomicAdd(&acc[2 * l], ea);
    atomicAdd(&acc[2 * l + 1], ea * az.y);
  }
  __syncthreads();
  float gb = wsum(gat_b[lane] * lin_W[lane]) + lin_b[0];
  float itmp = 1.f / tmp[0];
  {
    int e = b * 256 + t;
    float2 szv = asz[e];
    float eself = __expf(lrelu(szv.x + adl[t]));
    float la = (acc[2 * t + 1] + eself * szv.y) / (acc[2 * t] + eself) + gb;
    float ns = noise[e];
    float g = (logf(ns) - log1pf(-ns) + la) * itmp;
    float gate = 1.f / (1.f + __expf(-g));
    int key = row[e] * NN + col[e];
    unsigned hi = ((unsigned)key * 2654435761u) >> 14 & HMASK;
    while (true) {
      int old = atomicCAS(&hKeys[hi], -1, key);
      if (old == -1 || old == key) break;
      hi = (hi + 1) & HMASK;
    }
    atomic_pk_add_f16(&hPair[hi], packh2(1.0f, gate));
  }
}

// E: edge_mask -> w; CSR scatter packed u32: (w_bf16 << 16) | row(13b)
__global__ void kE(const int* __restrict__ row, const int* __restrict__ col,
                   const int* __restrict__ hKeys, const unsigned* __restrict__ hPair,
                   int* __restrict__ colCur, unsigned* __restrict__ csrW) {
  int e = blockIdx.x * 256 + threadIdx.x;
  int r = row[e], c = col[e];
  int s1 = hfind(hKeys, r * NN + c);
  unsigned u1 = hPair[s1];
  __half2 h1 = *reinterpret_cast<__half2*>(&u1);
  float cv = __low2float(h1), g1 = __high2float(h1);
  int s2 = hfind(hKeys, c * NN + r);
  float g2 = 0.f;
  if (s2 >= 0) {
    unsigned u2 = hPair[s2];
    g2 = __high2float(*reinterpret_cast<__half2*>(&u2));
  }
  float em = cv * 0.5f * (g1 + g2);
  float w = 1.f / (1.f + __expf(-em));
  int pos = atomicAdd(&colCur[c], 1);
  csrW[pos] = (f2bf1(w) << 16) | (unsigned)r;
}

// gather one node's aggregated features (fp8 rows = 128B, 4-wide ILP); returns f32 pair
__device__ __forceinline__ float2 gatherNode(const unsigned short* __restrict__ xb, int n, int lane,
                                             const int* __restrict__ colOffs,
                                             const unsigned* __restrict__ csrW) {
  float2 sf = fp8x2f(xb[n * 64 + lane]);
  float a0 = sf.x, a1 = sf.y, ws = 0.f;
  int off = colOffs[n], end = colOffs[n + 1];
  int i = off;
  for (; i + 4 <= end; i += 4) {
    unsigned q0 = csrW[i], q1 = csrW[i + 1], q2 = csrW[i + 2], q3 = csrW[i + 3];
    unsigned short u0 = xb[(q0 & 0x1fff) * 64 + lane];
    unsigned short u1 = xb[(q1 & 0x1fff) * 64 + lane];
    unsigned short u2 = xb[(q2 & 0x1fff) * 64 + lane];
    unsigned short u3 = xb[(q3 & 0x1fff) * 64 + lane];
    float w0 = bf1f(q0 >> 16), w1 = bf1f(q1 >> 16);
    float w2 = bf1f(q2 >> 16), w3 = bf1f(q3 >> 16);
    ws += w0 + w1 + w2 + w3;
    float2 f0 = fp8x2f(u0), f1 = fp8x2f(u1), f2v = fp8x2f(u2), f3 = fp8x2f(u3);
    a0 += w0 * f0.x + w1 * f1.x + w2 * f2v.x + w3 * f3.x;
    a1 += w0 * f0.y + w1 * f1.y + w2 * f2v.y + w3 * f3.y;
  }
  for (; i < end; i++) {
    unsigned q = csrW[i];
    unsigned short u = xb[(q & 0x1fff) * 64 + lane];
    float w = bf1f(q >> 16);
    ws += w;
    float2 f = fp8x2f(u);
    a0 += w * f.x;
    a1 += w * f.y;
  }
  float inv = 1.f / (1.f + ws);
  return make_float2(a0 * inv, a1 * inv);
}

// ---- GEMM: T in registers (lane L holds dims 2L,2L+1), W bf16 in 32KB LDS,
//      T[k] broadcast via scalar readlane ----
#define GEMM2(tv, acc)                                                   \
  {                                                                      \
    _Pragma("unroll") for (int j = 0; j < 2; j++) acc[j] = make_float2(0.f, 0.f); \
    _Pragma("unroll 16") for (int k2 = 0; k2 < 64; k2++) {               \
      float2 w0 = bf2f(Wl[(2 * k2) * 64 + lane]);                        \
      float2 w1 = bf2f(Wl[(2 * k2 + 1) * 64 + lane]);                    \
      _Pragma("unroll") for (int j = 0; j < 2; j++) {                    \
        float bx = rdlane(tv[j].x, k2);                                  \
        float by = rdlane(tv[j].y, k2);                                  \
        acc[j].x += bx * w0.x + by * w1.x;                               \
        acc[j].y += bx * w0.y + by * w1.y;                               \
      }                                                                  \
    }                                                                    \
  }

// F: GCN layer, 8 nodes/block (2 per wave), LDS = 32KB.
__global__ __launch_bounds__(256) void kF(const unsigned short* __restrict__ xb,
                                          const int* __restrict__ colOffs,
                                          const unsigned* __restrict__ csrW,
                                          const float* __restrict__ W,
                                          unsigned short* __restrict__ outB) {
  __shared__ unsigned Wl[128 * 64];  // bf16x2: Wl[k*64+l] = W[k][2l..2l+1]
  int t = threadIdx.x, lane = t & 63, wv = t >> 6;
  const float4* W4 = (const float4*)W;
  for (int i = t; i < 4096; i += 256) {
    float4 a = W4[i];
    ((uint2*)Wl)[i] = make_uint2(f2bf(a.x, a.y), f2bf(a.z, a.w));
  }
  int nb = blockIdx.x * 8;
  float2 tv[2];
#pragma unroll
  for (int j = 0; j < 2; j++)
    tv[j] = gatherNode(xb, nb + wv * 2 + j, lane, colOffs, csrW);
  __syncthreads();
  float2 acc[2];
  GEMM2(tv, acc)
#pragma unroll
  for (int j = 0; j < 2; j++) {
    int n = nb + wv * 2 + j;
    outB[n * 64 + lane] = f2fp8x2(fmaxf(acc[j].x, 0.f), fmaxf(acc[j].y, 0.f));
  }
}

// H: layer3 + pool + final. Pool accumulation spread over 16 gvec copies.
__global__ __launch_bounds__(256) void kH(const unsigned short* __restrict__ xb,
                                          const int* __restrict__ colOffs,
                                          const unsigned* __restrict__ csrW,
                                          const float* __restrict__ W,
                                          const float* __restrict__ Wc,
                                          float* __restrict__ gvec, unsigned* __restrict__ done,
                                          float* __restrict__ out) {
  __shared__ unsigned Wl[128 * 64];
  int t = threadIdx.x, lane = t & 63, wv = t >> 6;
  const float4* W4 = (const float4*)W;
  for (int i = t; i < 4096; i += 256) {
    float4 a = W4[i];
    ((uint2*)Wl)[i] = make_uint2(f2bf(a.x, a.y), f2bf(a.z, a.w));
  }
  int nb = blockIdx.x * 8;
  float2 tv[2];
#pragma unroll
  for (int j = 0; j < 2; j++)
    tv[j] = gatherNode(xb, nb + wv * 2 + j, lane, colOffs, csrW);
  __syncthreads();
  float2 acc[2];
  GEMM2(tv, acc)
  // pool: H3 never written to memory
  float s0 = fmaxf(acc[0].x, 0.f) + fmaxf(acc[1].x, 0.f);
  float s1 = fmaxf(acc[0].y, 0.f) + fmaxf(acc[1].y, 0.f);
  __syncthreads();  // GEMM done reading Wl; reuse as scratch
  float* gpart = (float*)Wl;
  unsigned* flagp = (unsigned*)Wl + 600;
  if (t < 128) gpart[t] = 0.f;
  __syncthreads();
  atomicAdd(&gpart[2 * lane], s0);
  atomicAdd(&gpart[2 * lane + 1], s1);
  __syncthreads();
  if (t < 128) atomicAdd(&gvec[((blockIdx.x & 15) << 7) + t], gpart[t]);
  asm volatile("s_waitcnt vmcnt(0)" ::: "memory");  // gvec atomics complete (memory-side)
  __syncthreads();
  if (t == 0) *flagp = (atomicAdd(done, 1u) == gridDim.x - 1) ? 1u : 0u;
  __syncthreads();
  if (*flagp) {
    float* f0 = (float*)Wl + 256;
    float* f1 = (float*)Wl + 384;
    if (t < 128) {
      float gj = 0.f;
#pragma unroll
      for (int k = 0; k < 16; k++) gj += atomicAdd(&gvec[k * 128 + t], 0.f);  // memory-side reads
      gj *= (1.0f / 8192.0f);
      f0[t] = gj * Wc[t * 2 + 0];
      f1[t] = gj * Wc[t * 2 + 1];
    }
    __syncthreads();
    for (int o = 64; o > 0; o >>= 1) {
      if (t < o) { f0[t] += f0[t + o]; f1[t] += f1[t + o]; }
      __syncthreads();
    }
    if (t == 0) {
      float l0 = f0[0], l1 = f1[0];
      float m = fmaxf(l0, l1);
      float e0 = __expf(l0 - m), e1 = __expf(l1 - m);
      float inv = 1.f / (e0 + e1);
      out[0] = e0 * inv;
      out[1] = e1 * inv;
    }
  }
}

extern "C" void kernel_launch(void* const* d_in, const int* in_sizes, int n_in,
                              void* d_out, int out_size, void* d_ws, size_t ws_size,
                              hipStream_t stream) {
  const float* x     = (const float*)d_in[0];
  const float* embed = (const float*)d_in[1];
  const float* noise = (const float*)d_in[2];
  const float* tmp   = (const float*)d_in[3];
  const float* gat_W = (const float*)d_in[4];
  const float* att_s = (const float*)d_in[5];
  const float* att_d = (const float*)d_in[6];
  const float* gat_b = (const float*)d_in[7];
  const float* lin_W = (const float*)d_in[8];
  const float* lin_b = (const float*)d_in[9];
  const float* W1    = (const float*)d_in[10];
  const float* W2    = (const float*)d_in[11];
  const float* W3    = (const float*)d_in[12];
  const float* Wc    = (const float*)d_in[13];
  const int* ei      = (const int*)d_in[14];
  const int* nei     = (const int*)d_in[15];
  const int* row = ei;
  const int* col = ei + EE;
  const int* src2 = nei;
  const int* dst2 = nei + E2C;
  float* out = (float*)d_out;

  // workspace layout (4-byte units); 16B/8B-aligned buffers first
  char* w8 = (char*)d_ws;
  size_t off = 0;
  auto alloc = [&](size_t units) -> void* {
    void* p = w8 + off * 4;
    off += units;
    return p;
  };
  float4*   pN      = (float4*)alloc(4 * NN);
  float4*   qN      = (float4*)alloc(4 * NN);
  float2*   asz     = (float2*)alloc(2 * EE);
  unsigned short* xbu = (unsigned short*)alloc(NN * 32);  // fp8x2 per lane
  unsigned short* H1u = (unsigned short*)alloc(NN * 32);
  unsigned short* H2u = (unsigned short*)alloc(NN * 32);
  unsigned* csrW    = (unsigned*)alloc(EE);
  float*    ad      = (float*)alloc(EE);
  int*      colCnt  = (int*)alloc(NN);
  int*      colOffs = (int*)alloc(NN + 2);
  int*      colCur  = (int*)alloc(NN);
  int*      hKeys   = (int*)alloc(HSZ);
  unsigned* hPair   = (unsigned*)alloc(HSZ);
  unsigned* bucket  = (unsigned*)alloc((size_t)NBIN * BCAP);
  unsigned* gCur    = (unsigned*)alloc(NBIN);
  float*    gvec    = (float*)alloc(2048);  // 16 copies x 128
  unsigned* done    = (unsigned*)alloc(2);

  kA<<<512, 256, 0, stream>>>(x, embed, gat_W, att_s, att_d, lin_W, pN, qN, xbu,
                              hKeys, hPair, colCnt, gvec, done, gCur);
  kC<<<NBIN, 256, 0, stream>>>(row, col, pN, qN, asz, ad, colCnt, src2, dst2, gCur, bucket);
  kD<<<NBIN + 1, 256, 0, stream>>>(row, col, asz, ad, bucket, gCur, gat_b, lin_W,
                                   lin_b, noise, tmp, hKeys, hPair, colCnt, colOffs, colCur);
  kE<<<EE / 256, 256, 0, stream>>>(row, col, hKeys, hPair, colCur, csrW);
  kF<<<NN / 8, 256, 0, stream>>>(xbu, colOffs, csrW, W1, H1u);
  kF<<<NN / 8, 256, 0, stream>>>(H1u, colOffs, csrW, W2, H2u);
  kH<<<NN / 8, 256, 0, stream>>>(H2u, colOffs, csrW, W3, Wc, gvec, done, out);
}

// Round 15
// 221.940 us; speedup vs baseline: 1.8328x; 1.0197x over previous
//
#include <hip/hip_runtime.h>
#include <hip/hip_fp16.h>
#include <math.h>

typedef unsigned long long u64;
typedef __attribute__((ext_vector_type(2))) float fv2;

#define NN 8192
#define EE 81920
#define E2C 1310720
#define HSZ (1 << 18)
#define HMASK (HSZ - 1)
#define NBIN 320     // dst >> 8 : bins of 256 edge-nodes
#define BCAP 4800    // Poisson(4096), +11 sigma
#define SBITS 17     // src index bits in packed u32 payload

__device__ __forceinline__ float wsum(float v) {
#pragma unroll
  for (int m = 32; m > 0; m >>= 1) v += __shfl_xor(v, m, 64);
  return v;
}
__device__ __forceinline__ float lrelu(float x) { return x > 0.f ? x : 0.2f * x; }
__device__ __forceinline__ unsigned packh2(float a, float b) {
  __half2 h = __floats2half2_rn(a, b);
  return *reinterpret_cast<unsigned*>(&h);
}
__device__ __forceinline__ void atomic_pk_add_f16(unsigned* addr, unsigned data) {
  asm volatile("global_atomic_pk_add_f16 %0, %1, off" :: "v"(addr), "v"(data) : "memory");
}
__device__ __forceinline__ int hfind(const int* __restrict__ keys, int key) {
  unsigned i = ((unsigned)key * 2654435761u) >> 14 & HMASK;
  while (true) {
    int k = keys[i];
    if (k == key) return (int)i;
    if (k == -1) return -1;
    i = (i + 1) & HMASK;
  }
}
// bf16 helpers
__device__ __forceinline__ float2 bf2f(unsigned u) {
  return make_float2(__uint_as_float(u << 16), __uint_as_float(u & 0xffff0000u));
}
__device__ __forceinline__ unsigned f2bf(float a, float b) {
  unsigned ua = __float_as_uint(a);
  ua = (ua + 0x7fffu + ((ua >> 16) & 1u)) >> 16;
  unsigned ub = __float_as_uint(b);
  ub = ((ub + 0x7fffu + ((ub >> 16) & 1u)) >> 16) << 16;
  return (ua & 0xffffu) | ub;
}
__device__ __forceinline__ unsigned f2bf1(float a) {
  unsigned ua = __float_as_uint(a);
  return (ua + 0x7fffu + ((ua >> 16) & 1u)) >> 16;
}
__device__ __forceinline__ float bf1f(unsigned u) { return __uint_as_float(u << 16); }
// fp8 e4m3 pack/unpack (HW cvt, gfx950 OCP)
__device__ __forceinline__ unsigned short f2fp8x2(float a, float b) {
  return (unsigned short)(__builtin_amdgcn_cvt_pk_fp8_f32(a, b, 0, false) & 0xffff);
}
__device__ __forceinline__ float2 fp8x2f(unsigned short v) {
  fv2 f = __builtin_amdgcn_cvt_pk_f32_fp8((int)(unsigned)v, false);
  return make_float2(f[0], f[1]);
}
// wave-uniform broadcast of lane k's value via scalar readlane (no LDS traffic)
__device__ __forceinline__ float rdlane(float v, int k) {
  return __uint_as_float(__builtin_amdgcn_readlane(__float_as_uint(v), k));
}

// A: init + x->fp8 + per-block combo in LDS + node scalars + gb scalar. 512 blocks.
__global__ __launch_bounds__(256) void kA(const float* __restrict__ x,
                                          const float* __restrict__ embed,
                                          const float* __restrict__ gw,
                                          const float* __restrict__ att_s,
                                          const float* __restrict__ att_d,
                                          const float* __restrict__ lin_W,
                                          const float* __restrict__ gat_b,
                                          const float* __restrict__ lin_b,
                                          float4* __restrict__ pN, float4* __restrict__ qN,
                                          unsigned short* __restrict__ xbu,
                                          int* __restrict__ hKeys, unsigned* __restrict__ hPair,
                                          int* __restrict__ colCnt, float* __restrict__ gvec,
                                          unsigned* __restrict__ done, unsigned* __restrict__ gCur,
                                          float* __restrict__ gbS) {
  __shared__ float sm[768];  // cA | cD | cZ
  int t = threadIdx.x, bid = blockIdx.x;
  int lane = t & 63, wv = t >> 6;
  for (int i = bid * 256 + t; i < HSZ; i += 512 * 256) { hKeys[i] = -1; hPair[i] = 0u; }
  for (int i = bid * 256 + t; i < NN; i += 512 * 256) colCnt[i] = 0;
  if (bid == 0) {
    for (int i = t; i < 2048; i += 256) gvec[i] = 0.f;  // 16 contention-spread copies
    if (t == 0) *done = 0u;
    for (int i = t; i < NBIN; i += 256) gCur[i] = 0u;
    if (wv == 0) {  // gb = gat_b . lin_W + lin_b, hoisted out of kD's 320 blocks
      float gb = wsum(gat_b[lane] * lin_W[lane]);
      if (lane == 0) *gbS = gb + lin_b[0];
    }
  }
  {  // x -> fp8 e4m3: thread handles node bid*16+(t>>4), dims (t&15)*8 .. +7
    int n = bid * 16 + (t >> 4);
    int dp = (t & 15) * 8;
    const float4* x4 = (const float4*)(x + n * 128 + dp);
    float4 a = x4[0], b = x4[1];
    unsigned p0 = f2fp8x2(a.x, a.y), p1 = f2fp8x2(a.z, a.w);
    unsigned p2 = f2fp8x2(b.x, b.y), p3 = f2fp8x2(b.z, b.w);
    ((uint2*)xbu)[n * 16 + (t & 15)] = make_uint2(p0 | (p1 << 16), p2 | (p3 << 16));
  }
  {
    float sa = 0.f, sd = 0.f, sz = 0.f;
#pragma unroll 8
    for (int k = 0; k < 64; k++) {
      float w = gw[t * 64 + k];
      sa += w * att_s[k]; sd += w * att_d[k]; sz += w * lin_W[k];
    }
    sm[t] = sa; sm[256 + t] = sd; sm[512 + t] = sz;
  }
  __syncthreads();
#pragma unroll
  for (int j = 0; j < 4; j++) {
    int n = bid * 16 + wv * 4 + j;
    float e0 = embed[n * 128 + lane], e1 = embed[n * 128 + 64 + lane];
    float pA = wsum(e0 * sm[lane] + e1 * sm[64 + lane]);
    float qA = wsum(e0 * sm[128 + lane] + e1 * sm[192 + lane]);
    float pD = wsum(e0 * sm[256 + lane] + e1 * sm[320 + lane]);
    float qD = wsum(e0 * sm[384 + lane] + e1 * sm[448 + lane]);
    float pZ = wsum(e0 * sm[512 + lane] + e1 * sm[576 + lane]);
    float qZ = wsum(e0 * sm[640 + lane] + e1 * sm[704 + lane]);
    if (lane == 0) pN[n] = make_float4(pA, pD, pZ, 0.f);
    if (lane == 1) qN[n] = make_float4(qA, qD, qZ, 0.f);
  }
}

// C: 320 blocks. Each block: (1) per-edge scalars for its 256 edges, (2) partition
// its 4096 edge2 entries into bins. colCnt scan lives in kD.
__global__ __launch_bounds__(256) void kC(const int* __restrict__ row, const int* __restrict__ col,
                                          const float4* __restrict__ pN, const float4* __restrict__ qN,
                                          float2* __restrict__ asz, float* __restrict__ ad,
                                          int* __restrict__ colCnt,
                                          const int* __restrict__ src2, const int* __restrict__ dst2,
                                          unsigned* __restrict__ gCur, unsigned* __restrict__ bucket) {
  __shared__ unsigned hist[NBIN], base[NBIN], lcur[NBIN];
  int t = threadIdx.x;
  for (int i = t; i < NBIN; i += 256) { hist[i] = 0u; lcur[i] = 0u; }
  int blockBase = blockIdx.x * 4096;
  {
    int e = blockIdx.x * 256 + t;
    int r = row[e], c = col[e];
    float4 p = pN[r];
    float4 q = qN[c];
    asz[e] = make_float2(p.x + q.x, p.z + q.z);  // {a_s, z}
    ad[e] = p.y + q.y;
    atomicAdd(&colCnt[c], 1);
  }
  __syncthreads();
  int4 dv[4];
#pragma unroll
  for (int j = 0; j < 4; j++) {
    dv[j] = *(const int4*)&dst2[blockBase + j * 1024 + t * 4];
    atomicAdd(&hist[dv[j].x >> 8], 1u);
    atomicAdd(&hist[dv[j].y >> 8], 1u);
    atomicAdd(&hist[dv[j].z >> 8], 1u);
    atomicAdd(&hist[dv[j].w >> 8], 1u);
  }
  __syncthreads();
  for (int i = t; i < NBIN; i += 256)
    if (hist[i]) base[i] = atomicAdd(&gCur[i], hist[i]);
  __syncthreads();
#pragma unroll
  for (int j = 0; j < 4; j++) {
    int4 sv = *(const int4*)&src2[blockBase + j * 1024 + t * 4];
    int ss[4] = {sv.x, sv.y, sv.z, sv.w};
    int dd[4] = {dv[j].x, dv[j].y, dv[j].z, dv[j].w};
#pragma unroll
    for (int k = 0; k < 4; k++) {
      int s = ss[k], d = dd[k];
      int b = d >> 8;
      unsigned r = atomicAdd(&lcur[b], 1u);
      unsigned pos = base[b] + r;
      if (pos < BCAP) bucket[(size_t)b * BCAP + pos] = ((unsigned)(d & 255) << SBITS) | (unsigned)s;
    }
  }
}

// D: blocks 0..319: per-bin reduce + gate + hash insert (records slot in eslot).
//    block 320: exclusive scan of colCnt -> colOffs/colCur.
__global__ __launch_bounds__(256) void kD(const int* __restrict__ row, const int* __restrict__ col,
                                          const float2* __restrict__ asz, const float* __restrict__ ad,
                                          const unsigned* __restrict__ bucket, const unsigned* __restrict__ gCur,
                                          const float* __restrict__ gbS,
                                          const float* __restrict__ noise,
                                          const float* __restrict__ tmp,
                                          int* __restrict__ hKeys, unsigned* __restrict__ hPair,
                                          int* __restrict__ eslot,
                                          const int* __restrict__ colCnt, int* __restrict__ colOffs,
                                          int* __restrict__ colCur) {
  __shared__ float acc[512];
  __shared__ float adl[256];
  int b = blockIdx.x, t = threadIdx.x;
  if (b == NBIN) {  // scan block
    __shared__ int sd32[256];
    int beg = t * 32;
    int s = 0;
#pragma unroll 8
    for (int i = 0; i < 32; i++) s += colCnt[beg + i];
    sd32[t] = s;
    __syncthreads();
    for (int o = 1; o < 256; o <<= 1) {
      int v = (t >= o) ? sd32[t - o] : 0;
      __syncthreads();
      sd32[t] += v;
      __syncthreads();
    }
    int run = (t == 0) ? 0 : sd32[t - 1];
    for (int i = 0; i < 32; i++) {
      colOffs[beg + i] = run;
      colCur[beg + i] = run;
      run += colCnt[beg + i];
    }
    if (t == 255) colOffs[NN] = run;
    return;
  }
  acc[2 * t] = 0.f; acc[2 * t + 1] = 0.f; adl[t] = ad[b * 256 + t];
  __syncthreads();
  int cnt = min((int)gCur[b], BCAP);
  const unsigned* bp = bucket + (size_t)b * BCAP;
  const unsigned SM = (1u << SBITS) - 1;
  int i = t;
  for (; i + 768 < cnt; i += 1024) {
    unsigned u0 = bp[i], u1 = bp[i + 256], u2 = bp[i + 512], u3 = bp[i + 768];
    float2 az0 = asz[u0 & SM], az1 = asz[u1 & SM], az2 = asz[u2 & SM], az3 = asz[u3 & SM];
    int l0 = u0 >> SBITS, l1 = u1 >> SBITS, l2 = u2 >> SBITS, l3 = u3 >> SBITS;
    float ea0 = __expf(lrelu(az0.x + adl[l0]));
    float ea1 = __expf(lrelu(az1.x + adl[l1]));
    float ea2 = __expf(lrelu(az2.x + adl[l2]));
    float ea3 = __expf(lrelu(az3.x + adl[l3]));
    atomicAdd(&acc[2 * l0], ea0); atomicAdd(&acc[2 * l0 + 1], ea0 * az0.y);
    atomicAdd(&acc[2 * l1], ea1); atomicAdd(&acc[2 * l1 + 1], ea1 * az1.y);
    atomicAdd(&acc[2 * l2], ea2); atomicAdd(&acc[2 * l2 + 1], ea2 * az2.y);
    atomicAdd(&acc[2 * l3], ea3); atomicAdd(&acc[2 * l3 + 1], ea3 * az3.y);
  }
  for (; i < cnt; i += 256) {
    unsigned u = bp[i];
    float2 az = asz[u & SM];
    int l = u >> SBITS;
    float ea = __expf(lrelu(az.x + adl[l]));
    atomicAdd(&acc[2 * l], ea);
    atomicAdd(&acc[2 * l + 1], ea * az.y);
  }
  __syncthreads();
  float gb = *gbS;
  float itmp = 1.f / tmp[0];
  {
    int e = b * 256 + t;
    float2 szv = asz[e];
    float eself = __expf(lrelu(szv.x + adl[t]));  // softmax shift-invariant
    float la = (acc[2 * t + 1] + eself * szv.y) / (acc[2 * t] + eself) + gb;
    float ns = noise[e];
    float g = (logf(ns) - log1pf(-ns) + la) * itmp;
    float gate = 1.f / (1.f + __expf(-g));
    int key = row[e] * NN + col[e];
    unsigned hi = ((unsigned)key * 2654435761u) >> 14 & HMASK;
    while (true) {
      int old = atomicCAS(&hKeys[hi], -1, key);
      if (old == -1 || old == key) break;
      hi = (hi + 1) & HMASK;
    }
    eslot[e] = (int)hi;  // forward slot for kE (skips its probe)
    atomic_pk_add_f16(&hPair[hi], packh2(1.0f, gate));
  }
}

// E: edge_mask -> w; forward slot precomputed (eslot), reverse still probes.
// CSR scatter packed u32: (w_bf16 << 16) | row(13b)
__global__ void kE(const int* __restrict__ row, const int* __restrict__ col,
                   const int* __restrict__ hKeys, const unsigned* __restrict__ hPair,
                   const int* __restrict__ eslot,
                   int* __restrict__ colCur, unsigned* __restrict__ csrW) {
  int e = blockIdx.x * 256 + threadIdx.x;
  int r = row[e], c = col[e];
  int s1 = eslot[e];
  unsigned u1 = hPair[s1];
  __half2 h1 = *reinterpret_cast<__half2*>(&u1);
  float cv = __low2float(h1), g1 = __high2float(h1);
  int s2 = hfind(hKeys, c * NN + r);
  float g2 = 0.f;
  if (s2 >= 0) {
    unsigned u2 = hPair[s2];
    g2 = __high2float(*reinterpret_cast<__half2*>(&u2));
  }
  float em = cv * 0.5f * (g1 + g2);
  float w = 1.f / (1.f + __expf(-em));
  int pos = atomicAdd(&colCur[c], 1);
  csrW[pos] = (f2bf1(w) << 16) | (unsigned)r;
}

// gather one node's aggregated features (fp8 rows = 128B, 4-wide ILP); returns f32 pair
__device__ __forceinline__ float2 gatherNode(const unsigned short* __restrict__ xb, int n, int lane,
                                             const int* __restrict__ colOffs,
                                             const unsigned* __restrict__ csrW) {
  float2 sf = fp8x2f(xb[n * 64 + lane]);
  float a0 = sf.x, a1 = sf.y, ws = 0.f;
  int off = colOffs[n], end = colOffs[n + 1];
  int i = off;
  for (; i + 4 <= end; i += 4) {
    unsigned q0 = csrW[i], q1 = csrW[i + 1], q2 = csrW[i + 2], q3 = csrW[i + 3];
    unsigned short u0 = xb[(q0 & 0x1fff) * 64 + lane];
    unsigned short u1 = xb[(q1 & 0x1fff) * 64 + lane];
    unsigned short u2 = xb[(q2 & 0x1fff) * 64 + lane];
    unsigned short u3 = xb[(q3 & 0x1fff) * 64 + lane];
    float w0 = bf1f(q0 >> 16), w1 = bf1f(q1 >> 16);
    float w2 = bf1f(q2 >> 16), w3 = bf1f(q3 >> 16);
    ws += w0 + w1 + w2 + w3;
    float2 f0 = fp8x2f(u0), f1 = fp8x2f(u1), f2v = fp8x2f(u2), f3 = fp8x2f(u3);
    a0 += w0 * f0.x + w1 * f1.x + w2 * f2v.x + w3 * f3.x;
    a1 += w0 * f0.y + w1 * f1.y + w2 * f2v.y + w3 * f3.y;
  }
  for (; i < end; i++) {
    unsigned q = csrW[i];
    unsigned short u = xb[(q & 0x1fff) * 64 + lane];
    float w = bf1f(q >> 16);
    ws += w;
    float2 f = fp8x2f(u);
    a0 += w * f.x;
    a1 += w * f.y;
  }
  float inv = 1.f / (1.f + ws);
  return make_float2(a0 * inv, a1 * inv);
}

// ---- GEMM: T in registers (lane L holds dims 2L,2L+1), W bf16 in 32KB LDS,
//      T[k] broadcast via scalar readlane ----
#define GEMM2(tv, acc)                                                   \
  {                                                                      \
    _Pragma("unroll") for (int j = 0; j < 2; j++) acc[j] = make_float2(0.f, 0.f); \
    _Pragma("unroll 16") for (int k2 = 0; k2 < 64; k2++) {               \
      float2 w0 = bf2f(Wl[(2 * k2) * 64 + lane]);                        \
      float2 w1 = bf2f(Wl[(2 * k2 + 1) * 64 + lane]);                    \
      _Pragma("unroll") for (int j = 0; j < 2; j++) {                    \
        float bx = rdlane(tv[j].x, k2);                                  \
        float by = rdlane(tv[j].y, k2);                                  \
        acc[j].x += bx * w0.x + by * w1.x;                               \
        acc[j].y += bx * w0.y + by * w1.y;                               \
      }                                                                  \
    }                                                                    \
  }

// F: GCN layer, 8 nodes/block (2 per wave), LDS = 32KB.
__global__ __launch_bounds__(256) void kF(const unsigned short* __restrict__ xb,
                                          const int* __restrict__ colOffs,
                                          const unsigned* __restrict__ csrW,
                                          const float* __restrict__ W,
                                          unsigned short* __restrict__ outB) {
  __shared__ unsigned Wl[128 * 64];  // bf16x2: Wl[k*64+l] = W[k][2l..2l+1]
  int t = threadIdx.x, lane = t & 63, wv = t >> 6;
  const float4* W4 = (const float4*)W;
  for (int i = t; i < 4096; i += 256) {
    float4 a = W4[i];
    ((uint2*)Wl)[i] = make_uint2(f2bf(a.x, a.y), f2bf(a.z, a.w));
  }
  int nb = blockIdx.x * 8;
  float2 tv[2];
#pragma unroll
  for (int j = 0; j < 2; j++)
    tv[j] = gatherNode(xb, nb + wv * 2 + j, lane, colOffs, csrW);
  __syncthreads();
  float2 acc[2];
  GEMM2(tv, acc)
#pragma unroll
  for (int j = 0; j < 2; j++) {
    int n = nb + wv * 2 + j;
    outB[n * 64 + lane] = f2fp8x2(fmaxf(acc[j].x, 0.f), fmaxf(acc[j].y, 0.f));
  }
}

// H: layer3 + pool + final. Pool accumulation spread over 16 gvec copies.
__global__ __launch_bounds__(256) void kH(const unsigned short* __restrict__ xb,
                                          const int* __restrict__ colOffs,
                                          const unsigned* __restrict__ csrW,
                                          const float* __restrict__ W,
                                          const float* __restrict__ Wc,
                                          float* __restrict__ gvec, unsigned* __restrict__ done,
                                          float* __restrict__ out) {
  __shared__ unsigned Wl[128 * 64];
  int t = threadIdx.x, lane = t & 63, wv = t >> 6;
  const float4* W4 = (const float4*)W;
  for (int i = t; i < 4096; i += 256) {
    float4 a = W4[i];
    ((uint2*)Wl)[i] = make_uint2(f2bf(a.x, a.y), f2bf(a.z, a.w));
  }
  int nb = blockIdx.x * 8;
  float2 tv[2];
#pragma unroll
  for (int j = 0; j < 2; j++)
    tv[j] = gatherNode(xb, nb + wv * 2 + j, lane, colOffs, csrW);
  __syncthreads();
  float2 acc[2];
  GEMM2(tv, acc)
  // pool: H3 never written to memory
  float s0 = fmaxf(acc[0].x, 0.f) + fmaxf(acc[1].x, 0.f);
  float s1 = fmaxf(acc[0].y, 0.f) + fmaxf(acc[1].y, 0.f);
  __syncthreads();  // GEMM done reading Wl; reuse as scratch
  float* gpart = (float*)Wl;
  unsigned* flagp = (unsigned*)Wl + 600;
  if (t < 128) gpart[t] = 0.f;
  __syncthreads();
  atomicAdd(&gpart[2 * lane], s0);
  atomicAdd(&gpart[2 * lane + 1], s1);
  __syncthreads();
  if (t < 128) atomicAdd(&gvec[((blockIdx.x & 15) << 7) + t], gpart[t]);
  asm volatile("s_waitcnt vmcnt(0)" ::: "memory");  // gvec atomics complete (memory-side)
  __syncthreads();
  if (t == 0) *flagp = (atomicAdd(done, 1u) == gridDim.x - 1) ? 1u : 0u;
  __syncthreads();
  if (*flagp) {
    float* f0 = (float*)Wl + 256;
    float* f1 = (float*)Wl + 384;
    if (t < 128) {
      float gj = 0.f;
#pragma unroll
      for (int k = 0; k < 16; k++) gj += atomicAdd(&gvec[k * 128 + t], 0.f);  // memory-side reads
      gj *= (1.0f / 8192.0f);
      f0[t] = gj * Wc[t * 2 + 0];
      f1[t] = gj * Wc[t * 2 + 1];
    }
    __syncthreads();
    for (int o = 64; o > 0; o >>= 1) {
      if (t < o) { f0[t] += f0[t + o]; f1[t] += f1[t + o]; }
      __syncthreads();
    }
    if (t == 0) {
      float l0 = f0[0], l1 = f1[0];
      float m = fmaxf(l0, l1);
      float e0 = __expf(l0 - m), e1 = __expf(l1 - m);
      float inv = 1.f / (e0 + e1);
      out[0] = e0 * inv;
      out[1] = e1 * inv;
    }
  }
}

extern "C" void kernel_launch(void* const* d_in, const int* in_sizes, int n_in,
                              void* d_out, int out_size, void* d_ws, size_t ws_size,
                              hipStream_t stream) {
  const float* x     = (const float*)d_in[0];
  const float* embed = (const float*)d_in[1];
  const float* noise = (const float*)d_in[2];
  const float* tmp   = (const float*)d_in[3];
  const float* gat_W = (const float*)d_in[4];
  const float* att_s = (const float*)d_in[5];
  const float* att_d = (const float*)d_in[6];
  const float* gat_b = (const float*)d_in[7];
  const float* lin_W = (const float*)d_in[8];
  const float* lin_b = (const float*)d_in[9];
  const float* W1    = (const float*)d_in[10];
  const float* W2    = (const float*)d_in[11];
  const float* W3    = (const float*)d_in[12];
  const float* Wc    = (const float*)d_in[13];
  const int* ei      = (const int*)d_in[14];
  const int* nei     = (const int*)d_in[15];
  const int* row = ei;
  const int* col = ei + EE;
  const int* src2 = nei;
  const int* dst2 = nei + E2C;
  float* out = (float*)d_out;

  // workspace layout (4-byte units); 16B/8B-aligned buffers first
  char* w8 = (char*)d_ws;
  size_t off = 0;
  auto alloc = [&](size_t units) -> void* {
    void* p = w8 + off * 4;
    off += units;
    return p;
  };
  float4*   pN      = (float4*)alloc(4 * NN);
  float4*   qN      = (float4*)alloc(4 * NN);
  float2*   asz     = (float2*)alloc(2 * EE);
  unsigned short* xbu = (unsigned short*)alloc(NN * 32);  // fp8x2 per lane
  unsigned short* H1u = (unsigned short*)alloc(NN * 32);
  unsigned short* H2u = (unsigned short*)alloc(NN * 32);
  unsigned* csrW    = (unsigned*)alloc(EE);
  float*    ad      = (float*)alloc(EE);
  int*      eslot   = (int*)alloc(EE);
  int*      colCnt  = (int*)alloc(NN);
  int*      colOffs = (int*)alloc(NN + 2);
  int*      colCur  = (int*)alloc(NN);
  int*      hKeys   = (int*)alloc(HSZ);
  unsigned* hPair   = (unsigned*)alloc(HSZ);
  unsigned* bucket  = (unsigned*)alloc((size_t)NBIN * BCAP);
  unsigned* gCur    = (unsigned*)alloc(NBIN);
  float*    gvec    = (float*)alloc(2048);  // 16 copies x 128
  unsigned* done    = (unsigned*)alloc(2);
  float*    gbS     = (float*)alloc(2);

  kA<<<512, 256, 0, stream>>>(x, embed, gat_W, att_s, att_d, lin_W, gat_b, lin_b,
                              pN, qN, xbu, hKeys, hPair, colCnt, gvec, done, gCur, gbS);
  kC<<<NBIN, 256, 0, stream>>>(row, col, pN, qN, asz, ad, colCnt, src2, dst2, gCur, bucket);
  kD<<<NBIN + 1, 256, 0, stream>>>(row, col, asz, ad, bucket, gCur, gbS, noise, tmp,
                                   hKeys, hPair, eslot, colCnt, colOffs, colCur);
  kE<<<EE / 256, 256, 0, stream>>>(row, col, hKeys, hPair, eslot, colCur, csrW);
  kF<<<NN / 8, 256, 0, stream>>>(xbu, colOffs, csrW, W1, H1u);
  kF<<<NN / 8, 256, 0, stream>>>(H1u, colOffs, csrW, W2, H2u);
  kH<<<NN / 8, 256, 0, stream>>>(H2u, colOffs, csrW, W3, Wc, gvec, done, out);
}